// Round 12
// baseline (276.175 us; speedup 1.0000x reference)
//
#include <hip/hip_runtime.h>
#include <hip/hip_bf16.h>

// LiteMLA: B=8, C=256, H=W=64, N=HW=4096, td=256, d=8, heads=64
// ws: qkv bf16 (8,768,4096) | agg bf16 (8,768,4096) | att_f bf16 (8,64,4096,8)
//     | w_projbf bf16 (256,512) | kvb f32 (8,64,72)
// Overlays (stream-order safe):
//   attf region: kvpart (16 x 36864 f32) at +0 ; wqbf (768x256 bf16) at +4194304
//   agg region:  xT bf16 [b][4096][256] at +0 (consumed by qkv_gemm BEFORE
//                dw_agg writes agg)
// Pipeline: prep_w, prep_wq, prep_xt, qkv_gemm (8-wave 64x32/wave, LDS-free),
//           dw_agg, kv_pass (MFMA), kv_red, att_pass, proj_gemm (8-wave)

#define HW 4096
#define ATT_EPS 1e-15f
#define BN_EPS 1e-6f

typedef __attribute__((ext_vector_type(8))) short short8;
typedef __attribute__((ext_vector_type(4))) short short4v;
typedef __attribute__((ext_vector_type(4))) float f32x4;
typedef __attribute__((ext_vector_type(2))) float f32x2;
typedef __attribute__((ext_vector_type(8))) unsigned short u16x8;
typedef __attribute__((ext_vector_type(4))) unsigned short u16x4;

static __device__ inline short f2bf(float f) {
    union { float f; unsigned u; } v; v.f = f;
    unsigned r = v.u + 0x7fff + ((v.u >> 16) & 1);   // RNE, finite inputs
    return (short)(r >> 16);
}
static __device__ inline float bf2f(unsigned short u) {
    union { unsigned u; float f; } v; v.u = (unsigned)u << 16; return v.f;
}

// ---------------- K0: w_proj f32 -> bf16 (256x512) ----------------
__global__ __launch_bounds__(256) void prep_w(const float* __restrict__ wproj,
                                              unsigned short* __restrict__ wbf) {
    const int i = (blockIdx.x * 256 + threadIdx.x) * 4;
    float4 v = *(const float4*)&wproj[i];
    u16x4 r = {(unsigned short)f2bf(v.x), (unsigned short)f2bf(v.y),
               (unsigned short)f2bf(v.z), (unsigned short)f2bf(v.w)};
    *(u16x4*)&wbf[i] = r;
}

// ---------------- K0b: w_qkv f32 -> bf16 (768x256) ----------------
__global__ __launch_bounds__(256) void prep_wq(const float* __restrict__ wqkv,
                                               unsigned short* __restrict__ wqbf) {
    const int i = (blockIdx.x * 256 + threadIdx.x) * 4;
    float4 v = *(const float4*)&wqkv[i];
    u16x4 r = {(unsigned short)f2bf(v.x), (unsigned short)f2bf(v.y),
               (unsigned short)f2bf(v.z), (unsigned short)f2bf(v.w)};
    *(u16x4*)&wqbf[i] = r;
}

// ---------------- K0c: x f32 [b][c][n] -> xT bf16 [b][n][c] ------------------
__global__ __launch_bounds__(256) void prep_xt(const float* __restrict__ x,
                                               unsigned short* __restrict__ xt) {
    __shared__ unsigned short tl[64][72];   // pitch 144B (16B-aligned rows)
    const int b = blockIdx.z;
    const int c0 = blockIdx.y * 64, n0 = blockIdx.x * 64;
    const int t = threadIdx.x;
    const int nq = t & 15, cl = t >> 4;     // n-quad, c-local base
#pragma unroll
    for (int p = 0; p < 4; p++) {
        const int c = cl + p * 16;
        float4 v = *(const float4*)&x[((size_t)b * 256 + c0 + c) * HW + n0 + nq * 4];
        tl[nq * 4 + 0][c] = (unsigned short)f2bf(v.x);
        tl[nq * 4 + 1][c] = (unsigned short)f2bf(v.y);
        tl[nq * 4 + 2][c] = (unsigned short)f2bf(v.z);
        tl[nq * 4 + 3][c] = (unsigned short)f2bf(v.w);
    }
    __syncthreads();
#pragma unroll
    for (int k = 0; k < 2; k++) {
        const int slot = t + 256 * k;           // 512 slots = 64n x 8 octets
        const int nl = slot >> 3, oct = slot & 7;
        u16x8 v = *(const u16x8*)&tl[nl][oct * 8];
        *(u16x8*)&xt[((size_t)b * 4096 + n0 + nl) * 256 + c0 + oct * 8] = v;
    }
}

// ---------------- K1: qkv = W(768x256) @ X — 8-wave LDS-free MFMA ------------
// R10 lesson: 4x4 acc tile (64 AGPR + 88 VGPR = 256-reg class) pins 2 waves/
// SIMD; prefetch can't rescue a 2-wave latency chain. Fix: 8 waves/block,
// 64x32 per wave -> acc[4][2] = 32 AGPR, ~100 unified regs = 128-reg class =
// 4 waves/SIMD (2x latency hiding). Block tile stays 128x128; dbuf kept.
__global__ __launch_bounds__(512) void qkv_gemm(const unsigned short* __restrict__ xt,
                                                const unsigned short* __restrict__ wqbf,
                                                unsigned short* __restrict__ qkv) {
    const int t  = threadIdx.x;
    const int b  = blockIdx.z;
    const int ob = blockIdx.y * 128;
    const int nb = blockIdx.x * 128;
    const int lane = t & 63, wave = t >> 6;
    const int wo = (wave >> 2) * 64, wn = (wave & 3) * 32;
    const int am = lane & 15, ak = lane >> 4;

    const unsigned short* ap0 = wqbf + (size_t)(ob + wo + am) * 256 + ak * 8;
    const unsigned short* bp0 = xt + ((size_t)b * 4096 + nb + wn + am) * 256 + ak * 8;

    f32x4 acc[4][2];
#pragma unroll
    for (int s = 0; s < 4; s++)
#pragma unroll
        for (int u = 0; u < 2; u++) acc[s][u] = (f32x4){0.f, 0.f, 0.f, 0.f};

    short8 afA[4], bfA[2], afB[4], bfB[2];

#define QLOAD(AF, BF, KB)                                                      \
    {                                                                          \
        _Pragma("unroll")                                                      \
        for (int s = 0; s < 4; s++)                                            \
            AF[s] = *(const short8*)(ap0 + (size_t)s * 16 * 256 + (KB));       \
        _Pragma("unroll")                                                      \
        for (int u = 0; u < 2; u++)                                            \
            BF[u] = *(const short8*)(bp0 + (size_t)u * 16 * 256 + (KB));       \
    }
#define QMM(AF, BF)                                                            \
    {                                                                          \
        _Pragma("unroll")                                                      \
        for (int s = 0; s < 4; s++)                                            \
            _Pragma("unroll")                                                  \
            for (int u = 0; u < 2; u++)                                        \
                acc[s][u] = __builtin_amdgcn_mfma_f32_16x16x32_bf16(           \
                    AF[s], BF[u], acc[s][u], 0, 0, 0);                         \
    }

    QLOAD(afA, bfA, 0)
#pragma unroll
    for (int kb = 0; kb < 256; kb += 64) {
        QLOAD(afB, bfB, kb + 32)
        QMM(afA, bfA)
        if (kb + 64 < 256) QLOAD(afA, bfA, kb + 64)
        QMM(afB, bfB)
    }
#undef QLOAD
#undef QMM

#pragma unroll
    for (int s = 0; s < 4; s++)
#pragma unroll
        for (int u = 0; u < 2; u++)
#pragma unroll
            for (int r = 0; r < 4; r++) {
                const int o = ob + wo + s * 16 + (lane >> 4) * 4 + r;
                const int nn = nb + wn + u * 16 + (lane & 15);
                qkv[((size_t)b * 768 + o) * HW + nn] = (unsigned short)f2bf(acc[s][u][r]);
            }
}

// ---------------- K2: fused dw5x5 + pw8x8 ------------------------------------
// Weights via block-uniform global pointers -> scalar pipe (R5 win). Tile f32
// [4ch][20r][64c] split 2x with refill (20.7 KB -> 6 blocks/CU). Accumulator
// out[8][4] = 32 f32 (R2: bigger spills).
__global__ __launch_bounds__(256, 6) void dw_agg(const unsigned short* __restrict__ qkv,
                                                 const float* __restrict__ wdw,
                                                 const float* __restrict__ wpw,
                                                 unsigned short* __restrict__ agg) {
    __shared__ float tile_raw[8 + 4 * 20 * 64 + 8];   // 20.7 KB
    float* tile = tile_raw + 8;
    const int b = blockIdx.z, g = blockIdx.y;
    const int y0 = blockIdx.x * 16;
    const int t = threadIdx.x;
    const int tx = t & 15, ty = t >> 4;     // col-quad, output row

    const float* wkg = wdw + g * 8 * 25;    // block-uniform -> scalar loads
    const float* pwg = wpw + g * 64;        // block-uniform -> scalar loads

    float out[8][4];
#pragma unroll
    for (int o = 0; o < 8; o++)
#pragma unroll
        for (int j = 0; j < 4; j++) out[o][j] = 0.f;

#pragma unroll 1
    for (int half = 0; half < 2; half++) {
        if (half) __syncthreads();          // all reads of prev half done
#pragma unroll
        for (int k = 0; k < 3; k++) {
            const int i = t + 256 * k;
            if (i < 640) {
                const int c8 = i & 7, rr = (i >> 3) % 20, ch = i / 160;
                const int y = y0 - 2 + rr;
                u16x8 v = {0, 0, 0, 0, 0, 0, 0, 0};
                if (y >= 0 && y < 64)
                    v = *(const u16x8*)&qkv[((size_t)(b * 768 + g * 8 + half * 4 + ch)) * HW + y * 64 + c8 * 8];
                f32x4 lo = {bf2f(v[0]), bf2f(v[1]), bf2f(v[2]), bf2f(v[3])};
                f32x4 hi = {bf2f(v[4]), bf2f(v[5]), bf2f(v[6]), bf2f(v[7])};
                *(f32x4*)&tile[i * 8]     = lo;
                *(f32x4*)&tile[i * 8 + 4] = hi;
            }
        }
        __syncthreads();

#pragma unroll 1
        for (int ch4 = 0; ch4 < 4; ch4++) {
            const int ch = half * 4 + ch4;
            const float* wkc = wkg + ch * 25;    // uniform -> SGPR
            float a0 = 0.f, a1 = 0.f, a2 = 0.f, a3 = 0.f;
#pragma unroll
            for (int dy = 0; dy < 5; dy++) {
                const int off = ch4 * 1280 + (ty + dy) * 64 + tx * 4;
                f32x4 C = *(const f32x4*)&tile[off];        // ds_read_b128
                f32x2 L = *(const f32x2*)&tile[off - 2];    // ds_read_b64
                f32x2 R = *(const f32x2*)&tile[off + 4];    // ds_read_b64
                float win[8];
                win[0] = (tx == 0)  ? 0.f : L[0];
                win[1] = (tx == 0)  ? 0.f : L[1];
                win[2] = C[0]; win[3] = C[1];
                win[4] = C[2]; win[5] = C[3];
                win[6] = (tx == 15) ? 0.f : R[0];
                win[7] = (tx == 15) ? 0.f : R[1];
#pragma unroll
                for (int dx = 0; dx < 5; dx++) {
                    const float wv = wkc[dy * 5 + dx];      // SGPR operand
                    a0 += wv * win[dx + 0];
                    a1 += wv * win[dx + 1];
                    a2 += wv * win[dx + 2];
                    a3 += wv * win[dx + 3];
                }
            }
#pragma unroll
            for (int o = 0; o < 8; o++) {
                const float wv = pwg[o * 8 + ch];           // SGPR operand
                out[o][0] += wv * a0; out[o][1] += wv * a1;
                out[o][2] += wv * a2; out[o][3] += wv * a3;
            }
        }
    }

#pragma unroll
    for (int o = 0; o < 8; o++) {
        u16x4 rv = {(unsigned short)f2bf(out[o][0]), (unsigned short)f2bf(out[o][1]),
                    (unsigned short)f2bf(out[o][2]), (unsigned short)f2bf(out[o][3])};
        *(u16x4*)&agg[((size_t)(b * 768 + g * 8 + o)) * HW + (y0 + ty) * 64 + tx * 4] = rv;
    }
}

// ---------------- K3: kv partials via MFMA (head-pair per wave) --------------
__global__ __launch_bounds__(256) void kv_pass(const unsigned short* __restrict__ qkv,
                                               const unsigned short* __restrict__ agg,
                                               float* __restrict__ kvpart) {
    const int t = threadIdx.x;
    const int w = t >> 6, lane = t & 63;
    const int hp = blockIdx.x * 4 + w;          // head-pair 0..31
    const int b = blockIdx.y, c = blockIdx.z;   // batch, n-chunk
    const int h0 = hp * 2, h1 = h0 + 1;         // same buf half always
    const unsigned short* buf = (h0 < 32) ? qkv : agg;
    const int cb0 = (h0 & 31) * 24, cb1 = (h1 & 31) * 24;

    const int row = lane & 15, kgrp = lane >> 4;
    const int n0 = c * 256 + kgrp * 8;

    const int chA = (row < 8) ? (cb0 + 8 + row) : (cb1 + row);
    const unsigned short* ap = buf + ((size_t)b * 768 + chA) * HW + n0;

    const bool bload = (row < 8);
    const unsigned short* bp0 = buf + ((size_t)b * 768 + cb0 + 16 + (row & 7)) * HW + n0;
    const unsigned short* bp1 = buf + ((size_t)b * 768 + cb1 + 16 + (row & 7)) * HW + n0;
    const short cfill = (row == 8) ? (short)0x3F80 : (short)0;   // bf16 1.0
    const short8 bconst = {cfill, cfill, cfill, cfill, cfill, cfill, cfill, cfill};

    f32x4 acc0 = {0.f, 0.f, 0.f, 0.f};
    f32x4 acc1 = {0.f, 0.f, 0.f, 0.f};

#pragma unroll
    for (int i = 0; i < 8; i++) {
        u16x8 av = *(const u16x8*)(ap + i * 32);
        short8 b0 = bload ? *(const short8*)(bp0 + i * 32) : bconst;
        short8 b1 = bload ? *(const short8*)(bp1 + i * 32) : bconst;
        short8 ar;
#pragma unroll
        for (int j = 0; j < 8; j++)
            ar[j] = (short)((av[j] & 0x8000) ? 0 : av[j]);    // relu on bf16 bits
        acc0 = __builtin_amdgcn_mfma_f32_16x16x32_bf16(ar, b0, acc0, 0, 0, 0);
        acc1 = __builtin_amdgcn_mfma_f32_16x16x32_bf16(ar, b1, acc1, 0, 0, 0);
    }

    if (row <= 8) {
        float* kp;
        f32x4 a;
        int dbase;
        if (kgrp < 2) {
            kp = kvpart + (size_t)c * 36864 + (size_t)(b * 64 + h0) * 72;
            a = acc0; dbase = kgrp * 4;
        } else {
            kp = kvpart + (size_t)c * 36864 + (size_t)(b * 64 + h1) * 72;
            a = acc1; dbase = (kgrp - 2) * 4;
        }
#pragma unroll
        for (int r = 0; r < 4; r++)
            kp[(dbase + r) * 9 + row] = a[r];
    }
}

// ---------------- K3b: sum the 16 kv partial chunks --------------------------
__global__ __launch_bounds__(256) void kv_red(const float* __restrict__ kvpart,
                                              float* __restrict__ kvout) {
    const int i = blockIdx.x * 256 + threadIdx.x;   // 144 blocks x 256 = 36864
    float s = 0.f;
#pragma unroll
    for (int c = 0; c < 16; c++) s += kvpart[(size_t)c * 36864 + i];
    kvout[i] = s;
}

// ---------------- K4: att -> att_f[b][h][n][8] (B-fragment-ready bf16) -------
__global__ __launch_bounds__(256) void att_pass(const unsigned short* __restrict__ qkv,
                                                const unsigned short* __restrict__ agg,
                                                const float* __restrict__ kvbuf,
                                                unsigned short* __restrict__ att_f) {
    const int h = blockIdx.y, b = blockIdx.z;
    const int t = threadIdx.x;
    const float* kvp = kvbuf + ((size_t)(b * 64 + h)) * 72;   // block-uniform

    float kvr[72];
#pragma unroll
    for (int i = 0; i < 18; i++) {
        f32x4 v = *(const f32x4*)&kvp[i * 4];
        kvr[i * 4 + 0] = v[0]; kvr[i * 4 + 1] = v[1];
        kvr[i * 4 + 2] = v[2]; kvr[i * 4 + 3] = v[3];
    }

    const unsigned short* buf = (h < 32) ? qkv : agg;
    const int cbase = (h & 31) * 24;
    const int n0 = (blockIdx.x * 256 + t) * 8;
    const unsigned short* qp = buf + ((size_t)b * 768 + cbase) * HW + n0;

    float q[8][8];
#pragma unroll
    for (int d = 0; d < 8; d++) {
        u16x8 v = *(const u16x8*)&qp[(size_t)d * HW];
#pragma unroll
        for (int j = 0; j < 8; j++) q[d][j] = fmaxf(bf2f(v[j]), 0.f);
    }

    unsigned short* op = att_f + (((size_t)(b * 64 + h)) * HW + n0) * 8;
#pragma unroll
    for (int j = 0; j < 8; j++) {
        float num[9];
#pragma unroll
        for (int e = 0; e < 9; e++) num[e] = 0.f;
#pragma unroll
        for (int d = 0; d < 8; d++) {
            const float qv = q[d][j];
#pragma unroll
            for (int e = 0; e < 9; e++) num[e] += qv * kvr[d * 9 + e];
        }
        const float rden = 1.f / (num[8] + ATT_EPS);
        u16x8 r;
#pragma unroll
        for (int e = 0; e < 8; e++) r[e] = (unsigned short)f2bf(num[e] * rden);
        *(u16x8*)&op[j * 8] = r;
    }
}

// ---------------- K5: p = Wp @ att, BN, +x — 8-wave LDS-free MFMA ------------
__global__ __launch_bounds__(512) void proj_gemm(const unsigned short* __restrict__ wbf,
                                                 const unsigned short* __restrict__ att_f,
                                                 const float* __restrict__ gamma,
                                                 const float* __restrict__ beta,
                                                 const float* __restrict__ mean,
                                                 const float* __restrict__ var,
                                                 const float* __restrict__ x,
                                                 float* __restrict__ out) {
    const int t  = threadIdx.x;
    const int b  = blockIdx.z;
    const int ob = blockIdx.y * 128;
    const int nb = blockIdx.x * 128;
    const int lane = t & 63, wave = t >> 6;
    const int wo = (wave >> 2) * 64, wn = (wave & 3) * 32;

    const int am = lane & 15, ak = lane >> 4;
    const unsigned short* ap0 = wbf + (size_t)(ob + wo + am) * 512 + ak * 8;
    const unsigned short* bp0 = att_f +
        (((size_t)b * 64 + ak) * HW + nb + wn + am) * 8;

    f32x4 acc[4][2];
#pragma unroll
    for (int s = 0; s < 4; s++)
#pragma unroll
        for (int u = 0; u < 2; u++) acc[s][u] = (f32x4){0.f, 0.f, 0.f, 0.f};

    short8 afA[4], bfA[2], afB[4], bfB[2];

#define PLOAD(AF, BF, KB)                                                      \
    {                                                                          \
        _Pragma("unroll")                                                      \
        for (int s = 0; s < 4; s++)                                            \
            AF[s] = *(const short8*)(ap0 + (size_t)s * 16 * 512 + (KB));       \
        _Pragma("unroll")                                                      \
        for (int u = 0; u < 2; u++)                                            \
            BF[u] = *(const short8*)(bp0 + ((size_t)((KB) >> 3) * HW + u * 16) * 8); \
    }
#define PMM(AF, BF)                                                            \
    {                                                                          \
        _Pragma("unroll")                                                      \
        for (int s = 0; s < 4; s++)                                            \
            _Pragma("unroll")                                                  \
            for (int u = 0; u < 2; u++)                                        \
                acc[s][u] = __builtin_amdgcn_mfma_f32_16x16x32_bf16(           \
                    AF[s], BF[u], acc[s][u], 0, 0, 0);                         \
    }

    PLOAD(afA, bfA, 0)
#pragma unroll
    for (int kb = 0; kb < 512; kb += 64) {
        PLOAD(afB, bfB, kb + 32)
        PMM(afA, bfA)
        if (kb + 64 < 512) PLOAD(afA, bfA, kb + 64)
        PMM(afB, bfB)
    }
#undef PLOAD
#undef PMM

#pragma unroll
    for (int s = 0; s < 4; s++) {
        const int o_base = ob + wo + s * 16 + (lane >> 4) * 4;
#pragma unroll
        for (int r = 0; r < 4; r++) {
            const int o = o_base + r;
            const float inv = gamma[o] * rsqrtf(var[o] + BN_EPS);
            const float sh  = beta[o] - mean[o] * inv;
#pragma unroll
            for (int u = 0; u < 2; u++) {
                const int n = nb + wn + u * 16 + (lane & 15);
                const size_t idx = ((size_t)b * 256 + o) * HW + n;
                out[idx] = x[idx] + acc[s][u][r] * inv + sh;
            }
        }
    }
}

extern "C" void kernel_launch(void* const* d_in, const int* in_sizes, int n_in,
                              void* d_out, int out_size, void* d_ws, size_t ws_size,
                              hipStream_t stream) {
    const float* x      = (const float*)d_in[0];
    const float* w_qkv  = (const float*)d_in[1];
    const float* w_dw   = (const float*)d_in[2];
    const float* w_pw   = (const float*)d_in[3];
    const float* w_proj = (const float*)d_in[4];
    const float* gamma  = (const float*)d_in[5];
    const float* beta   = (const float*)d_in[6];
    const float* mean   = (const float*)d_in[7];
    const float* var    = (const float*)d_in[8];
    float* out = (float*)d_out;

    unsigned short* qkv  = (unsigned short*)d_ws;      // 25165824 shorts
    unsigned short* agg  = qkv + (size_t)25165824;     // 25165824 shorts
    unsigned short* attf = agg + (size_t)25165824;     // 16777216 shorts
    unsigned short* wbf  = attf + (size_t)16777216;    // 131072 shorts
    float* kvb = (float*)(wbf + (size_t)131072);       // 36864 floats
    float* kvpart = (float*)attf;                      // 16*36864 f32, transient
    unsigned short* wqbf = attf + (size_t)4194304;     // 196608 shorts, transient
    unsigned short* xt   = agg;                        // 8388608 shorts, transient
                                                       // (agg written later by dw_agg)

    prep_w  <<<dim3(128),       256, 0, stream>>>(w_proj, wbf);
    prep_wq <<<dim3(192),       256, 0, stream>>>(w_qkv, wqbf);
    prep_xt <<<dim3(64, 4, 8),  256, 0, stream>>>(x, xt);
    qkv_gemm<<<dim3(32, 6, 8),  512, 0, stream>>>(xt, wqbf, qkv);
    dw_agg  <<<dim3(4, 96, 8),  256, 0, stream>>>(qkv, w_dw, w_pw, agg);
    kv_pass <<<dim3(8, 8, 16),  256, 0, stream>>>(qkv, agg, kvpart);
    kv_red  <<<dim3(144),       256, 0, stream>>>(kvpart, kvb);
    att_pass<<<dim3(2, 64, 8),  256, 0, stream>>>(qkv, agg, kvb, attf);
    proj_gemm<<<dim3(32, 2, 8), 512, 0, stream>>>(wbf, attf,
                                                  gamma, beta, mean, var, x, out);
}

// Round 13
// 226.515 us; speedup vs baseline: 1.2192x; 1.2192x over previous
//
#include <hip/hip_runtime.h>
#include <hip/hip_bf16.h>

// LiteMLA: B=8, C=256, H=W=64, N=HW=4096, td=256, d=8, heads=64
// ws: qkv bf16 (8,768,4096) | agg bf16 (8,768,4096) | att_f bf16 (8,64,4096,8)
//     | w_projbf bf16 (256,512) | kvb f32 (8,64,72)
// Overlays (stream-order safe):
//   attf region: kvpart (16 x 36864 f32) at +0 ; wqbf (768x256 bf16) at +4194304
//   agg region:  xT bf16 [b][4096][256] at +0 (consumed by qkv_gemm BEFORE
//                dw_agg writes agg)
// Pipeline: prep_w, prep_wq, prep_xt, qkv_gemm (barrier-staged LDS, all-vector
//           u16x8 staging from pre-transposed xt — R12 lesson: LDS-free direct
//           frags are a latency chain at ANY occupancy; R7/R8 lesson: in-kernel
//           transpose costs scalar LDS writes or gathers), dw_agg, kv_pass,
//           kv_red, att_pass, proj_gemm (R7 4-wave version)

#define HW 4096
#define ATT_EPS 1e-15f
#define BN_EPS 1e-6f

typedef __attribute__((ext_vector_type(8))) short short8;
typedef __attribute__((ext_vector_type(4))) short short4v;
typedef __attribute__((ext_vector_type(4))) float f32x4;
typedef __attribute__((ext_vector_type(2))) float f32x2;
typedef __attribute__((ext_vector_type(8))) unsigned short u16x8;
typedef __attribute__((ext_vector_type(4))) unsigned short u16x4;

static __device__ inline short f2bf(float f) {
    union { float f; unsigned u; } v; v.f = f;
    unsigned r = v.u + 0x7fff + ((v.u >> 16) & 1);   // RNE, finite inputs
    return (short)(r >> 16);
}
static __device__ inline float bf2f(unsigned short u) {
    union { unsigned u; float f; } v; v.u = (unsigned)u << 16; return v.f;
}

// ---------------- K0: w_proj f32 -> bf16 (256x512) ----------------
__global__ __launch_bounds__(256) void prep_w(const float* __restrict__ wproj,
                                              unsigned short* __restrict__ wbf) {
    const int i = (blockIdx.x * 256 + threadIdx.x) * 4;
    float4 v = *(const float4*)&wproj[i];
    u16x4 r = {(unsigned short)f2bf(v.x), (unsigned short)f2bf(v.y),
               (unsigned short)f2bf(v.z), (unsigned short)f2bf(v.w)};
    *(u16x4*)&wbf[i] = r;
}

// ---------------- K0b: w_qkv f32 -> bf16 (768x256) ----------------
__global__ __launch_bounds__(256) void prep_wq(const float* __restrict__ wqkv,
                                               unsigned short* __restrict__ wqbf) {
    const int i = (blockIdx.x * 256 + threadIdx.x) * 4;
    float4 v = *(const float4*)&wqkv[i];
    u16x4 r = {(unsigned short)f2bf(v.x), (unsigned short)f2bf(v.y),
               (unsigned short)f2bf(v.z), (unsigned short)f2bf(v.w)};
    *(u16x4*)&wqbf[i] = r;
}

// ---------------- K0c: x f32 [b][c][n] -> xT bf16 [b][n][c] ------------------
// The [k][n]->[n][k] transpose done ONCE (R8 lesson: in-GEMM transpose is paid
// 6x as scalar LDS writes or scalar gathers).
__global__ __launch_bounds__(256) void prep_xt(const float* __restrict__ x,
                                               unsigned short* __restrict__ xt) {
    __shared__ unsigned short tl[64][72];   // pitch 144B (16B-aligned rows)
    const int b = blockIdx.z;
    const int c0 = blockIdx.y * 64, n0 = blockIdx.x * 64;
    const int t = threadIdx.x;
    const int nq = t & 15, cl = t >> 4;     // n-quad, c-local base
#pragma unroll
    for (int p = 0; p < 4; p++) {
        const int c = cl + p * 16;
        float4 v = *(const float4*)&x[((size_t)b * 256 + c0 + c) * HW + n0 + nq * 4];
        tl[nq * 4 + 0][c] = (unsigned short)f2bf(v.x);
        tl[nq * 4 + 1][c] = (unsigned short)f2bf(v.y);
        tl[nq * 4 + 2][c] = (unsigned short)f2bf(v.z);
        tl[nq * 4 + 3][c] = (unsigned short)f2bf(v.w);
    }
    __syncthreads();
#pragma unroll
    for (int k = 0; k < 2; k++) {
        const int slot = t + 256 * k;           // 512 slots = 64n x 8 octets
        const int nl = slot >> 3, oct = slot & 7;
        u16x8 v = *(const u16x8*)&tl[nl][oct * 8];
        *(u16x8*)&xt[((size_t)b * 4096 + n0 + nl) * 256 + c0 + oct * 8] = v;
    }
}

// ---------------- K1: qkv = W(768x256) @ X — barrier-staged vector LDS -------
// R7 structure (43.5 us, proven) with its two diseases removed:
//  - B staging was 16 scalar ds_write_b16/thread (7.08M conflict cycles) ->
//    now u16x8 global load + ds_write_b128 from pre-transposed xt [n][k].
//  - 32 f2bf cvt/iter -> 0 (xt and wqbf already bf16).
// Pitch 40 u16 (80B, 16B-aligned rows): frag reads AND staged writes land at
// <=2-way bank aliasing (free, per guide m136). LDS ops/thread/iter: 28 -> 16.
__global__ __launch_bounds__(256) void qkv_gemm(const unsigned short* __restrict__ xt,
                                                const unsigned short* __restrict__ wqbf,
                                                unsigned short* __restrict__ qkv) {
    __shared__ unsigned short A_l[128 * 40];
    __shared__ unsigned short B_l[128 * 40];
    const int t  = threadIdx.x;
    const int b  = blockIdx.z;
    const int ob = blockIdx.y * 128;
    const int nb = blockIdx.x * 128;
    const int lane = t & 63, wave = t >> 6;
    const int wo = (wave >> 1) * 64, wn = (wave & 1) * 64;
    const int am = lane & 15, ak = lane >> 4;

    // staging: 512 slots per tile (128 rows x 4 chunks of 8 u16); 2 per thread
    const int r0 = t >> 2, c0 = t & 3;
    const unsigned short* asrc = wqbf + (size_t)(ob + r0) * 256 + c0 * 8;
    const unsigned short* bsrc = xt + ((size_t)b * 4096 + nb + r0) * 256 + c0 * 8;

    f32x4 acc[4][4];
#pragma unroll
    for (int s = 0; s < 4; s++)
#pragma unroll
        for (int u = 0; u < 4; u++) acc[s][u] = (f32x4){0.f, 0.f, 0.f, 0.f};

    for (int kb = 0; kb < 256; kb += 32) {
        __syncthreads();                 // prev-iter frag reads complete
        *(u16x8*)&A_l[r0 * 40 + c0 * 8] = *(const u16x8*)(asrc + kb);
        *(u16x8*)&A_l[(r0 + 64) * 40 + c0 * 8] =
            *(const u16x8*)(asrc + (size_t)64 * 256 + kb);
        *(u16x8*)&B_l[r0 * 40 + c0 * 8] = *(const u16x8*)(bsrc + kb);
        *(u16x8*)&B_l[(r0 + 64) * 40 + c0 * 8] =
            *(const u16x8*)(bsrc + (size_t)64 * 256 + kb);
        __syncthreads();

        short8 af[4], bf[4];
#pragma unroll
        for (int s = 0; s < 4; s++)
            af[s] = *(const short8*)&A_l[(wo + s * 16 + am) * 40 + ak * 8];
#pragma unroll
        for (int u = 0; u < 4; u++)
            bf[u] = *(const short8*)&B_l[(wn + u * 16 + am) * 40 + ak * 8];
#pragma unroll
        for (int s = 0; s < 4; s++)
#pragma unroll
            for (int u = 0; u < 4; u++)
                acc[s][u] = __builtin_amdgcn_mfma_f32_16x16x32_bf16(af[s], bf[u], acc[s][u], 0, 0, 0);
    }

#pragma unroll
    for (int s = 0; s < 4; s++)
#pragma unroll
        for (int u = 0; u < 4; u++)
#pragma unroll
            for (int r = 0; r < 4; r++) {
                const int o = ob + wo + s * 16 + (lane >> 4) * 4 + r;
                const int nn = nb + wn + u * 16 + (lane & 15);
                qkv[((size_t)b * 768 + o) * HW + nn] = (unsigned short)f2bf(acc[s][u][r]);
            }
}

// ---------------- K2: fused dw5x5 + pw8x8 ------------------------------------
// Weights via block-uniform global pointers -> scalar pipe (R5 win). Tile f32
// [4ch][20r][64c] split 2x with refill (20.7 KB -> 6 blocks/CU). Accumulator
// out[8][4] = 32 f32 (R2: bigger spills).
__global__ __launch_bounds__(256, 6) void dw_agg(const unsigned short* __restrict__ qkv,
                                                 const float* __restrict__ wdw,
                                                 const float* __restrict__ wpw,
                                                 unsigned short* __restrict__ agg) {
    __shared__ float tile_raw[8 + 4 * 20 * 64 + 8];   // 20.7 KB
    float* tile = tile_raw + 8;
    const int b = blockIdx.z, g = blockIdx.y;
    const int y0 = blockIdx.x * 16;
    const int t = threadIdx.x;
    const int tx = t & 15, ty = t >> 4;     // col-quad, output row

    const float* wkg = wdw + g * 8 * 25;    // block-uniform -> scalar loads
    const float* pwg = wpw + g * 64;        // block-uniform -> scalar loads

    float out[8][4];
#pragma unroll
    for (int o = 0; o < 8; o++)
#pragma unroll
        for (int j = 0; j < 4; j++) out[o][j] = 0.f;

#pragma unroll 1
    for (int half = 0; half < 2; half++) {
        if (half) __syncthreads();          // all reads of prev half done
#pragma unroll
        for (int k = 0; k < 3; k++) {
            const int i = t + 256 * k;
            if (i < 640) {
                const int c8 = i & 7, rr = (i >> 3) % 20, ch = i / 160;
                const int y = y0 - 2 + rr;
                u16x8 v = {0, 0, 0, 0, 0, 0, 0, 0};
                if (y >= 0 && y < 64)
                    v = *(const u16x8*)&qkv[((size_t)(b * 768 + g * 8 + half * 4 + ch)) * HW + y * 64 + c8 * 8];
                f32x4 lo = {bf2f(v[0]), bf2f(v[1]), bf2f(v[2]), bf2f(v[3])};
                f32x4 hi = {bf2f(v[4]), bf2f(v[5]), bf2f(v[6]), bf2f(v[7])};
                *(f32x4*)&tile[i * 8]     = lo;
                *(f32x4*)&tile[i * 8 + 4] = hi;
            }
        }
        __syncthreads();

#pragma unroll 1
        for (int ch4 = 0; ch4 < 4; ch4++) {
            const int ch = half * 4 + ch4;
            const float* wkc = wkg + ch * 25;    // uniform -> SGPR
            float a0 = 0.f, a1 = 0.f, a2 = 0.f, a3 = 0.f;
#pragma unroll
            for (int dy = 0; dy < 5; dy++) {
                const int off = ch4 * 1280 + (ty + dy) * 64 + tx * 4;
                f32x4 C = *(const f32x4*)&tile[off];        // ds_read_b128
                f32x2 L = *(const f32x2*)&tile[off - 2];    // ds_read_b64
                f32x2 R = *(const f32x2*)&tile[off + 4];    // ds_read_b64
                float win[8];
                win[0] = (tx == 0)  ? 0.f : L[0];
                win[1] = (tx == 0)  ? 0.f : L[1];
                win[2] = C[0]; win[3] = C[1];
                win[4] = C[2]; win[5] = C[3];
                win[6] = (tx == 15) ? 0.f : R[0];
                win[7] = (tx == 15) ? 0.f : R[1];
#pragma unroll
                for (int dx = 0; dx < 5; dx++) {
                    const float wv = wkc[dy * 5 + dx];      // SGPR operand
                    a0 += wv * win[dx + 0];
                    a1 += wv * win[dx + 1];
                    a2 += wv * win[dx + 2];
                    a3 += wv * win[dx + 3];
                }
            }
#pragma unroll
            for (int o = 0; o < 8; o++) {
                const float wv = pwg[o * 8 + ch];           // SGPR operand
                out[o][0] += wv * a0; out[o][1] += wv * a1;
                out[o][2] += wv * a2; out[o][3] += wv * a3;
            }
        }
    }

#pragma unroll
    for (int o = 0; o < 8; o++) {
        u16x4 rv = {(unsigned short)f2bf(out[o][0]), (unsigned short)f2bf(out[o][1]),
                    (unsigned short)f2bf(out[o][2]), (unsigned short)f2bf(out[o][3])};
        *(u16x4*)&agg[((size_t)(b * 768 + g * 8 + o)) * HW + (y0 + ty) * 64 + tx * 4] = rv;
    }
}

// ---------------- K3: kv partials via MFMA (head-pair per wave) --------------
__global__ __launch_bounds__(256) void kv_pass(const unsigned short* __restrict__ qkv,
                                               const unsigned short* __restrict__ agg,
                                               float* __restrict__ kvpart) {
    const int t = threadIdx.x;
    const int w = t >> 6, lane = t & 63;
    const int hp = blockIdx.x * 4 + w;          // head-pair 0..31
    const int b = blockIdx.y, c = blockIdx.z;   // batch, n-chunk
    const int h0 = hp * 2, h1 = h0 + 1;         // same buf half always
    const unsigned short* buf = (h0 < 32) ? qkv : agg;
    const int cb0 = (h0 & 31) * 24, cb1 = (h1 & 31) * 24;

    const int row = lane & 15, kgrp = lane >> 4;
    const int n0 = c * 256 + kgrp * 8;

    const int chA = (row < 8) ? (cb0 + 8 + row) : (cb1 + row);
    const unsigned short* ap = buf + ((size_t)b * 768 + chA) * HW + n0;

    const bool bload = (row < 8);
    const unsigned short* bp0 = buf + ((size_t)b * 768 + cb0 + 16 + (row & 7)) * HW + n0;
    const unsigned short* bp1 = buf + ((size_t)b * 768 + cb1 + 16 + (row & 7)) * HW + n0;
    const short cfill = (row == 8) ? (short)0x3F80 : (short)0;   // bf16 1.0
    const short8 bconst = {cfill, cfill, cfill, cfill, cfill, cfill, cfill, cfill};

    f32x4 acc0 = {0.f, 0.f, 0.f, 0.f};
    f32x4 acc1 = {0.f, 0.f, 0.f, 0.f};

#pragma unroll
    for (int i = 0; i < 8; i++) {
        u16x8 av = *(const u16x8*)(ap + i * 32);
        short8 b0 = bload ? *(const short8*)(bp0 + i * 32) : bconst;
        short8 b1 = bload ? *(const short8*)(bp1 + i * 32) : bconst;
        short8 ar;
#pragma unroll
        for (int j = 0; j < 8; j++)
            ar[j] = (short)((av[j] & 0x8000) ? 0 : av[j]);    // relu on bf16 bits
        acc0 = __builtin_amdgcn_mfma_f32_16x16x32_bf16(ar, b0, acc0, 0, 0, 0);
        acc1 = __builtin_amdgcn_mfma_f32_16x16x32_bf16(ar, b1, acc1, 0, 0, 0);
    }

    if (row <= 8) {
        float* kp;
        f32x4 a;
        int dbase;
        if (kgrp < 2) {
            kp = kvpart + (size_t)c * 36864 + (size_t)(b * 64 + h0) * 72;
            a = acc0; dbase = kgrp * 4;
        } else {
            kp = kvpart + (size_t)c * 36864 + (size_t)(b * 64 + h1) * 72;
            a = acc1; dbase = (kgrp - 2) * 4;
        }
#pragma unroll
        for (int r = 0; r < 4; r++)
            kp[(dbase + r) * 9 + row] = a[r];
    }
}

// ---------------- K3b: sum the 16 kv partial chunks --------------------------
__global__ __launch_bounds__(256) void kv_red(const float* __restrict__ kvpart,
                                              float* __restrict__ kvout) {
    const int i = blockIdx.x * 256 + threadIdx.x;   // 144 blocks x 256 = 36864
    float s = 0.f;
#pragma unroll
    for (int c = 0; c < 16; c++) s += kvpart[(size_t)c * 36864 + i];
    kvout[i] = s;
}

// ---------------- K4: att -> att_f[b][h][n][8] (B-fragment-ready bf16) -------
__global__ __launch_bounds__(256) void att_pass(const unsigned short* __restrict__ qkv,
                                                const unsigned short* __restrict__ agg,
                                                const float* __restrict__ kvbuf,
                                                unsigned short* __restrict__ att_f) {
    const int h = blockIdx.y, b = blockIdx.z;
    const int t = threadIdx.x;
    const float* kvp = kvbuf + ((size_t)(b * 64 + h)) * 72;   // block-uniform

    float kvr[72];
#pragma unroll
    for (int i = 0; i < 18; i++) {
        f32x4 v = *(const f32x4*)&kvp[i * 4];
        kvr[i * 4 + 0] = v[0]; kvr[i * 4 + 1] = v[1];
        kvr[i * 4 + 2] = v[2]; kvr[i * 4 + 3] = v[3];
    }

    const unsigned short* buf = (h < 32) ? qkv : agg;
    const int cbase = (h & 31) * 24;
    const int n0 = (blockIdx.x * 256 + t) * 8;
    const unsigned short* qp = buf + ((size_t)b * 768 + cbase) * HW + n0;

    float q[8][8];
#pragma unroll
    for (int d = 0; d < 8; d++) {
        u16x8 v = *(const u16x8*)&qp[(size_t)d * HW];
#pragma unroll
        for (int j = 0; j < 8; j++) q[d][j] = fmaxf(bf2f(v[j]), 0.f);
    }

    unsigned short* op = att_f + (((size_t)(b * 64 + h)) * HW + n0) * 8;
#pragma unroll
    for (int j = 0; j < 8; j++) {
        float num[9];
#pragma unroll
        for (int e = 0; e < 9; e++) num[e] = 0.f;
#pragma unroll
        for (int d = 0; d < 8; d++) {
            const float qv = q[d][j];
#pragma unroll
            for (int e = 0; e < 9; e++) num[e] += qv * kvr[d * 9 + e];
        }
        const float rden = 1.f / (num[8] + ATT_EPS);
        u16x8 r;
#pragma unroll
        for (int e = 0; e < 8; e++) r[e] = (unsigned short)f2bf(num[e] * rden);
        *(u16x8*)&op[j * 8] = r;
    }
}

// ---------------- K5: p = Wp @ att, BN, +x — LDS-free direct-frag MFMA -------
// R7 4-wave version (part of the 220.8 us best configuration).
__global__ __launch_bounds__(256) void proj_gemm(const unsigned short* __restrict__ wbf,
                                                 const unsigned short* __restrict__ att_f,
                                                 const float* __restrict__ gamma,
                                                 const float* __restrict__ beta,
                                                 const float* __restrict__ mean,
                                                 const float* __restrict__ var,
                                                 const float* __restrict__ x,
                                                 float* __restrict__ out) {
    const int t  = threadIdx.x;
    const int b  = blockIdx.z;
    const int ob = blockIdx.y * 128;
    const int nb = blockIdx.x * 128;
    const int lane = t & 63, wave = t >> 6;
    const int wo = (wave >> 1) * 64, wn = (wave & 1) * 64;

    const int am = lane & 15, ak = lane >> 4;
    const unsigned short* ap0 = wbf + (size_t)(ob + wo + am) * 512 + ak * 8;
    const unsigned short* bp0 = att_f +
        (((size_t)b * 64 + ak) * HW + nb + wn + am) * 8;

    f32x4 acc[4][4];
#pragma unroll
    for (int s = 0; s < 4; s++)
#pragma unroll
        for (int u = 0; u < 4; u++) acc[s][u] = (f32x4){0.f, 0.f, 0.f, 0.f};

    for (int kb = 0; kb < 512; kb += 32) {
        short8 af[4], bf[4];
#pragma unroll
        for (int s = 0; s < 4; s++)
            af[s] = *(const short8*)(ap0 + (size_t)s * 16 * 512 + kb);
#pragma unroll
        for (int u = 0; u < 4; u++)
            bf[u] = *(const short8*)(bp0 + ((size_t)(kb >> 3) * HW + u * 16) * 8);
#pragma unroll
        for (int s = 0; s < 4; s++)
#pragma unroll
            for (int u = 0; u < 4; u++)
                acc[s][u] = __builtin_amdgcn_mfma_f32_16x16x32_bf16(af[s], bf[u], acc[s][u], 0, 0, 0);
    }

#pragma unroll
    for (int s = 0; s < 4; s++) {
        const int o_base = ob + wo + s * 16 + (lane >> 4) * 4;
#pragma unroll
        for (int r = 0; r < 4; r++) {
            const int o = o_base + r;
            const float inv = gamma[o] * rsqrtf(var[o] + BN_EPS);
            const float sh  = beta[o] - mean[o] * inv;
#pragma unroll
            for (int u = 0; u < 4; u++) {
                const int n = nb + wn + u * 16 + (lane & 15);
                const size_t idx = ((size_t)b * 256 + o) * HW + n;
                out[idx] = x[idx] + acc[s][u][r] * inv + sh;
            }
        }
    }
}

extern "C" void kernel_launch(void* const* d_in, const int* in_sizes, int n_in,
                              void* d_out, int out_size, void* d_ws, size_t ws_size,
                              hipStream_t stream) {
    const float* x      = (const float*)d_in[0];
    const float* w_qkv  = (const float*)d_in[1];
    const float* w_dw   = (const float*)d_in[2];
    const float* w_pw   = (const float*)d_in[3];
    const float* w_proj = (const float*)d_in[4];
    const float* gamma  = (const float*)d_in[5];
    const float* beta   = (const float*)d_in[6];
    const float* mean   = (const float*)d_in[7];
    const float* var    = (const float*)d_in[8];
    float* out = (float*)d_out;

    unsigned short* qkv  = (unsigned short*)d_ws;      // 25165824 shorts
    unsigned short* agg  = qkv + (size_t)25165824;     // 25165824 shorts
    unsigned short* attf = agg + (size_t)25165824;     // 16777216 shorts
    unsigned short* wbf  = attf + (size_t)16777216;    // 131072 shorts
    float* kvb = (float*)(wbf + (size_t)131072);       // 36864 floats
    float* kvpart = (float*)attf;                      // 16*36864 f32, transient
    unsigned short* wqbf = attf + (size_t)4194304;     // 196608 shorts, transient
    unsigned short* xt   = agg;                        // 8388608 shorts, transient
                                                       // (agg written later by dw_agg)

    prep_w  <<<dim3(128),       256, 0, stream>>>(w_proj, wbf);
    prep_wq <<<dim3(192),       256, 0, stream>>>(w_qkv, wqbf);
    prep_xt <<<dim3(64, 4, 8),  256, 0, stream>>>(x, xt);
    qkv_gemm<<<dim3(32, 6, 8),  256, 0, stream>>>(xt, wqbf, qkv);
    dw_agg  <<<dim3(4, 96, 8),  256, 0, stream>>>(qkv, w_dw, w_pw, agg);
    kv_pass <<<dim3(8, 8, 16),  256, 0, stream>>>(qkv, agg, kvpart);
    kv_red  <<<dim3(144),       256, 0, stream>>>(kvpart, kvb);
    att_pass<<<dim3(2, 64, 8),  256, 0, stream>>>(qkv, agg, kvb, attf);
    proj_gemm<<<dim3(32, 2, 8), 256, 0, stream>>>(wbf, attf,
                                                  gamma, beta, mean, var, x, out);
}

// Round 14
// 224.512 us; speedup vs baseline: 1.2301x; 1.0089x over previous
//
#include <hip/hip_runtime.h>
#include <hip/hip_bf16.h>

// LiteMLA: B=8, C=256, H=W=64, N=HW=4096, td=256, d=8, heads=64
// ws: qkv bf16 (8,768,4096) | agg bf16 (8,768,4096) | att_f bf16 (8,64,4096,8)
//     | w_projbf bf16 (256,512) | kvb f32 (8,64,72)
// Overlays (stream-order safe):
//   attf region: kvpart (16 x 36864 f32) at +0 ; wqbf (768x256 bf16) at +4194304
//   agg region:  xT bf16 [b][4096][256] at +0 (consumed by qkv_gemm BEFORE
//                dw_agg writes agg)
// Pipeline: prep_w, prep_wq, prep_xt, qkv_gemm (barrier-staged vector LDS),
//           dw_agg (DPP-halo: x-halo via v_mov_dpp row-shift, LDS reads/thread
//           120->40), kv_pass (MFMA), kv_red, att_pass, proj_gemm

#define HW 4096
#define ATT_EPS 1e-15f
#define BN_EPS 1e-6f

typedef __attribute__((ext_vector_type(8))) short short8;
typedef __attribute__((ext_vector_type(4))) short short4v;
typedef __attribute__((ext_vector_type(4))) float f32x4;
typedef __attribute__((ext_vector_type(2))) float f32x2;
typedef __attribute__((ext_vector_type(8))) unsigned short u16x8;
typedef __attribute__((ext_vector_type(4))) unsigned short u16x4;

static __device__ inline short f2bf(float f) {
    union { float f; unsigned u; } v; v.f = f;
    unsigned r = v.u + 0x7fff + ((v.u >> 16) & 1);   // RNE, finite inputs
    return (short)(r >> 16);
}
static __device__ inline float bf2f(unsigned short u) {
    union { unsigned u; float f; } v; v.u = (unsigned)u << 16; return v.f;
}

// DPP 16-lane row shifts (VALU, not LDS). bound_ctrl=1 -> row-edge lanes get 0,
// which coincides exactly with the image x-boundary zero-padding (tx groups of
// 16 = one full 64-px image row; DPP rows are 16 lanes on gfx9).
static __device__ inline float dpp_shr1(float x) {      // lane i <- lane i-1
    int i = __builtin_bit_cast(int, x);
    int r = __builtin_amdgcn_update_dpp(0, i, 0x111, 0xF, 0xF, true);
    return __builtin_bit_cast(float, r);
}
static __device__ inline float dpp_shl1(float x) {      // lane i <- lane i+1
    int i = __builtin_bit_cast(int, x);
    int r = __builtin_amdgcn_update_dpp(0, i, 0x101, 0xF, 0xF, true);
    return __builtin_bit_cast(float, r);
}

// ---------------- K0: w_proj f32 -> bf16 (256x512) ----------------
__global__ __launch_bounds__(256) void prep_w(const float* __restrict__ wproj,
                                              unsigned short* __restrict__ wbf) {
    const int i = (blockIdx.x * 256 + threadIdx.x) * 4;
    float4 v = *(const float4*)&wproj[i];
    u16x4 r = {(unsigned short)f2bf(v.x), (unsigned short)f2bf(v.y),
               (unsigned short)f2bf(v.z), (unsigned short)f2bf(v.w)};
    *(u16x4*)&wbf[i] = r;
}

// ---------------- K0b: w_qkv f32 -> bf16 (768x256) ----------------
__global__ __launch_bounds__(256) void prep_wq(const float* __restrict__ wqkv,
                                               unsigned short* __restrict__ wqbf) {
    const int i = (blockIdx.x * 256 + threadIdx.x) * 4;
    float4 v = *(const float4*)&wqkv[i];
    u16x4 r = {(unsigned short)f2bf(v.x), (unsigned short)f2bf(v.y),
               (unsigned short)f2bf(v.z), (unsigned short)f2bf(v.w)};
    *(u16x4*)&wqbf[i] = r;
}

// ---------------- K0c: x f32 [b][c][n] -> xT bf16 [b][n][c] ------------------
__global__ __launch_bounds__(256) void prep_xt(const float* __restrict__ x,
                                               unsigned short* __restrict__ xt) {
    __shared__ unsigned short tl[64][72];   // pitch 144B (16B-aligned rows)
    const int b = blockIdx.z;
    const int c0 = blockIdx.y * 64, n0 = blockIdx.x * 64;
    const int t = threadIdx.x;
    const int nq = t & 15, cl = t >> 4;     // n-quad, c-local base
#pragma unroll
    for (int p = 0; p < 4; p++) {
        const int c = cl + p * 16;
        float4 v = *(const float4*)&x[((size_t)b * 256 + c0 + c) * HW + n0 + nq * 4];
        tl[nq * 4 + 0][c] = (unsigned short)f2bf(v.x);
        tl[nq * 4 + 1][c] = (unsigned short)f2bf(v.y);
        tl[nq * 4 + 2][c] = (unsigned short)f2bf(v.z);
        tl[nq * 4 + 3][c] = (unsigned short)f2bf(v.w);
    }
    __syncthreads();
#pragma unroll
    for (int k = 0; k < 2; k++) {
        const int slot = t + 256 * k;           // 512 slots = 64n x 8 octets
        const int nl = slot >> 3, oct = slot & 7;
        u16x8 v = *(const u16x8*)&tl[nl][oct * 8];
        *(u16x8*)&xt[((size_t)b * 4096 + n0 + nl) * 256 + c0 + oct * 8] = v;
    }
}

// ---------------- K1: qkv = W(768x256) @ X — barrier-staged vector LDS -------
// R13-verified (dropped out of top-5): all-u16x8 staging from pre-transposed
// xt, zero conversions, pitch-40 rows.
__global__ __launch_bounds__(256) void qkv_gemm(const unsigned short* __restrict__ xt,
                                                const unsigned short* __restrict__ wqbf,
                                                unsigned short* __restrict__ qkv) {
    __shared__ unsigned short A_l[128 * 40];
    __shared__ unsigned short B_l[128 * 40];
    const int t  = threadIdx.x;
    const int b  = blockIdx.z;
    const int ob = blockIdx.y * 128;
    const int nb = blockIdx.x * 128;
    const int lane = t & 63, wave = t >> 6;
    const int wo = (wave >> 1) * 64, wn = (wave & 1) * 64;
    const int am = lane & 15, ak = lane >> 4;

    const int r0 = t >> 2, c0 = t & 3;
    const unsigned short* asrc = wqbf + (size_t)(ob + r0) * 256 + c0 * 8;
    const unsigned short* bsrc = xt + ((size_t)b * 4096 + nb + r0) * 256 + c0 * 8;

    f32x4 acc[4][4];
#pragma unroll
    for (int s = 0; s < 4; s++)
#pragma unroll
        for (int u = 0; u < 4; u++) acc[s][u] = (f32x4){0.f, 0.f, 0.f, 0.f};

    for (int kb = 0; kb < 256; kb += 32) {
        __syncthreads();                 // prev-iter frag reads complete
        *(u16x8*)&A_l[r0 * 40 + c0 * 8] = *(const u16x8*)(asrc + kb);
        *(u16x8*)&A_l[(r0 + 64) * 40 + c0 * 8] =
            *(const u16x8*)(asrc + (size_t)64 * 256 + kb);
        *(u16x8*)&B_l[r0 * 40 + c0 * 8] = *(const u16x8*)(bsrc + kb);
        *(u16x8*)&B_l[(r0 + 64) * 40 + c0 * 8] =
            *(const u16x8*)(bsrc + (size_t)64 * 256 + kb);
        __syncthreads();

        short8 af[4], bf[4];
#pragma unroll
        for (int s = 0; s < 4; s++)
            af[s] = *(const short8*)&A_l[(wo + s * 16 + am) * 40 + ak * 8];
#pragma unroll
        for (int u = 0; u < 4; u++)
            bf[u] = *(const short8*)&B_l[(wn + u * 16 + am) * 40 + ak * 8];
#pragma unroll
        for (int s = 0; s < 4; s++)
#pragma unroll
            for (int u = 0; u < 4; u++)
                acc[s][u] = __builtin_amdgcn_mfma_f32_16x16x32_bf16(af[s], bf[u], acc[s][u], 0, 0, 0);
    }

#pragma unroll
    for (int s = 0; s < 4; s++)
#pragma unroll
        for (int u = 0; u < 4; u++)
#pragma unroll
            for (int r = 0; r < 4; r++) {
                const int o = ob + wo + s * 16 + (lane >> 4) * 4 + r;
                const int nn = nb + wn + u * 16 + (lane & 15);
                qkv[((size_t)b * 768 + o) * HW + nn] = (unsigned short)f2bf(acc[s][u][r]);
            }
}

// ---------------- K2: fused dw5x5 + pw8x8, DPP halo --------------------------
// R13 counters: 120 LDS reads/thread (3 per ch,dy) + 160 edge-selects were the
// cost. Now: 1 ds_read_b128 per (ch,dy); x-halo via 4 v_mov_dpp row-shifts
// (VALU pipe, auto-zero at row edges == image boundary). LDS reads/thread 40.
// Weights via scalar pipe (R5); tile f32 [4ch][20r][64c] split 2x (20 KB);
// accumulator 32 f32 (R2: bigger spills).
__global__ __launch_bounds__(256, 6) void dw_agg(const unsigned short* __restrict__ qkv,
                                                 const float* __restrict__ wdw,
                                                 const float* __restrict__ wpw,
                                                 unsigned short* __restrict__ agg) {
    __shared__ float tile[4 * 20 * 64];     // 20 KB
    const int b = blockIdx.z, g = blockIdx.y;
    const int y0 = blockIdx.x * 16;
    const int t = threadIdx.x;
    const int tx = t & 15, ty = t >> 4;     // col-quad, output row

    const float* wkg = wdw + g * 8 * 25;    // block-uniform -> scalar loads
    const float* pwg = wpw + g * 64;        // block-uniform -> scalar loads

    float out[8][4];
#pragma unroll
    for (int o = 0; o < 8; o++)
#pragma unroll
        for (int j = 0; j < 4; j++) out[o][j] = 0.f;

#pragma unroll 1
    for (int half = 0; half < 2; half++) {
        if (half) __syncthreads();          // all reads of prev half done
        // fill: 640 octet-slots (4ch x 20r x 8 col-octets); bf16->f32 once.
#pragma unroll
        for (int k = 0; k < 3; k++) {
            const int i = t + 256 * k;
            if (i < 640) {
                const int c8 = i & 7, rr = (i >> 3) % 20, ch = i / 160;
                const int y = y0 - 2 + rr;
                u16x8 v = {0, 0, 0, 0, 0, 0, 0, 0};
                if (y >= 0 && y < 64)
                    v = *(const u16x8*)&qkv[((size_t)(b * 768 + g * 8 + half * 4 + ch)) * HW + y * 64 + c8 * 8];
                f32x4 lo = {bf2f(v[0]), bf2f(v[1]), bf2f(v[2]), bf2f(v[3])};
                f32x4 hi = {bf2f(v[4]), bf2f(v[5]), bf2f(v[6]), bf2f(v[7])};
                *(f32x4*)&tile[i * 8]     = lo;
                *(f32x4*)&tile[i * 8 + 4] = hi;
            }
        }
        __syncthreads();

#pragma unroll 1
        for (int ch4 = 0; ch4 < 4; ch4++) {
            const int ch = half * 4 + ch4;
            const float* wkc = wkg + ch * 25;    // uniform -> SGPR
            float a0 = 0.f, a1 = 0.f, a2 = 0.f, a3 = 0.f;
#pragma unroll
            for (int dy = 0; dy < 5; dy++) {
                const int off = ch4 * 1280 + (ty + dy) * 64 + tx * 4;
                f32x4 C = *(const f32x4*)&tile[off];    // the ONLY LDS read
                float win[8];
                win[0] = dpp_shr1(C[2]);    // lane-1's C[2]; 0 at tx==0
                win[1] = dpp_shr1(C[3]);
                win[2] = C[0]; win[3] = C[1];
                win[4] = C[2]; win[5] = C[3];
                win[6] = dpp_shl1(C[0]);    // lane+1's C[0]; 0 at tx==15
                win[7] = dpp_shl1(C[1]);
#pragma unroll
                for (int dx = 0; dx < 5; dx++) {
                    const float wv = wkc[dy * 5 + dx];      // SGPR operand
                    a0 += wv * win[dx + 0];
                    a1 += wv * win[dx + 1];
                    a2 += wv * win[dx + 2];
                    a3 += wv * win[dx + 3];
                }
            }
#pragma unroll
            for (int o = 0; o < 8; o++) {
                const float wv = pwg[o * 8 + ch];           // SGPR operand
                out[o][0] += wv * a0; out[o][1] += wv * a1;
                out[o][2] += wv * a2; out[o][3] += wv * a3;
            }
        }
    }

#pragma unroll
    for (int o = 0; o < 8; o++) {
        u16x4 rv = {(unsigned short)f2bf(out[o][0]), (unsigned short)f2bf(out[o][1]),
                    (unsigned short)f2bf(out[o][2]), (unsigned short)f2bf(out[o][3])};
        *(u16x4*)&agg[((size_t)(b * 768 + g * 8 + o)) * HW + (y0 + ty) * 64 + tx * 4] = rv;
    }
}

// ---------------- K3: kv partials via MFMA (head-pair per wave) --------------
__global__ __launch_bounds__(256) void kv_pass(const unsigned short* __restrict__ qkv,
                                               const unsigned short* __restrict__ agg,
                                               float* __restrict__ kvpart) {
    const int t = threadIdx.x;
    const int w = t >> 6, lane = t & 63;
    const int hp = blockIdx.x * 4 + w;          // head-pair 0..31
    const int b = blockIdx.y, c = blockIdx.z;   // batch, n-chunk
    const int h0 = hp * 2, h1 = h0 + 1;         // same buf half always
    const unsigned short* buf = (h0 < 32) ? qkv : agg;
    const int cb0 = (h0 & 31) * 24, cb1 = (h1 & 31) * 24;

    const int row = lane & 15, kgrp = lane >> 4;
    const int n0 = c * 256 + kgrp * 8;

    const int chA = (row < 8) ? (cb0 + 8 + row) : (cb1 + row);
    const unsigned short* ap = buf + ((size_t)b * 768 + chA) * HW + n0;

    const bool bload = (row < 8);
    const unsigned short* bp0 = buf + ((size_t)b * 768 + cb0 + 16 + (row & 7)) * HW + n0;
    const unsigned short* bp1 = buf + ((size_t)b * 768 + cb1 + 16 + (row & 7)) * HW + n0;
    const short cfill = (row == 8) ? (short)0x3F80 : (short)0;   // bf16 1.0
    const short8 bconst = {cfill, cfill, cfill, cfill, cfill, cfill, cfill, cfill};

    f32x4 acc0 = {0.f, 0.f, 0.f, 0.f};
    f32x4 acc1 = {0.f, 0.f, 0.f, 0.f};

#pragma unroll
    for (int i = 0; i < 8; i++) {
        u16x8 av = *(const u16x8*)(ap + i * 32);
        short8 b0 = bload ? *(const short8*)(bp0 + i * 32) : bconst;
        short8 b1 = bload ? *(const short8*)(bp1 + i * 32) : bconst;
        short8 ar;
#pragma unroll
        for (int j = 0; j < 8; j++)
            ar[j] = (short)((av[j] & 0x8000) ? 0 : av[j]);    // relu on bf16 bits
        acc0 = __builtin_amdgcn_mfma_f32_16x16x32_bf16(ar, b0, acc0, 0, 0, 0);
        acc1 = __builtin_amdgcn_mfma_f32_16x16x32_bf16(ar, b1, acc1, 0, 0, 0);
    }

    if (row <= 8) {
        float* kp;
        f32x4 a;
        int dbase;
        if (kgrp < 2) {
            kp = kvpart + (size_t)c * 36864 + (size_t)(b * 64 + h0) * 72;
            a = acc0; dbase = kgrp * 4;
        } else {
            kp = kvpart + (size_t)c * 36864 + (size_t)(b * 64 + h1) * 72;
            a = acc1; dbase = (kgrp - 2) * 4;
        }
#pragma unroll
        for (int r = 0; r < 4; r++)
            kp[(dbase + r) * 9 + row] = a[r];
    }
}

// ---------------- K3b: sum the 16 kv partial chunks --------------------------
__global__ __launch_bounds__(256) void kv_red(const float* __restrict__ kvpart,
                                              float* __restrict__ kvout) {
    const int i = blockIdx.x * 256 + threadIdx.x;   // 144 blocks x 256 = 36864
    float s = 0.f;
#pragma unroll
    for (int c = 0; c < 16; c++) s += kvpart[(size_t)c * 36864 + i];
    kvout[i] = s;
}

// ---------------- K4: att -> att_f[b][h][n][8] (B-fragment-ready bf16) -------
__global__ __launch_bounds__(256) void att_pass(const unsigned short* __restrict__ qkv,
                                                const unsigned short* __restrict__ agg,
                                                const float* __restrict__ kvbuf,
                                                unsigned short* __restrict__ att_f) {
    const int h = blockIdx.y, b = blockIdx.z;
    const int t = threadIdx.x;
    const float* kvp = kvbuf + ((size_t)(b * 64 + h)) * 72;   // block-uniform

    float kvr[72];
#pragma unroll
    for (int i = 0; i < 18; i++) {
        f32x4 v = *(const f32x4*)&kvp[i * 4];
        kvr[i * 4 + 0] = v[0]; kvr[i * 4 + 1] = v[1];
        kvr[i * 4 + 2] = v[2]; kvr[i * 4 + 3] = v[3];
    }

    const unsigned short* buf = (h < 32) ? qkv : agg;
    const int cbase = (h & 31) * 24;
    const int n0 = (blockIdx.x * 256 + t) * 8;
    const unsigned short* qp = buf + ((size_t)b * 768 + cbase) * HW + n0;

    float q[8][8];
#pragma unroll
    for (int d = 0; d < 8; d++) {
        u16x8 v = *(const u16x8*)&qp[(size_t)d * HW];
#pragma unroll
        for (int j = 0; j < 8; j++) q[d][j] = fmaxf(bf2f(v[j]), 0.f);
    }

    unsigned short* op = att_f + (((size_t)(b * 64 + h)) * HW + n0) * 8;
#pragma unroll
    for (int j = 0; j < 8; j++) {
        float num[9];
#pragma unroll
        for (int e = 0; e < 9; e++) num[e] = 0.f;
#pragma unroll
        for (int d = 0; d < 8; d++) {
            const float qv = q[d][j];
#pragma unroll
            for (int e = 0; e < 9; e++) num[e] += qv * kvr[d * 9 + e];
        }
        const float rden = 1.f / (num[8] + ATT_EPS);
        u16x8 r;
#pragma unroll
        for (int e = 0; e < 8; e++) r[e] = (unsigned short)f2bf(num[e] * rden);
        *(u16x8*)&op[j * 8] = r;
    }
}

// ---------------- K5: p = Wp @ att, BN, +x — LDS-free direct-frag MFMA -------
__global__ __launch_bounds__(256) void proj_gemm(const unsigned short* __restrict__ wbf,
                                                 const unsigned short* __restrict__ att_f,
                                                 const float* __restrict__ gamma,
                                                 const float* __restrict__ beta,
                                                 const float* __restrict__ mean,
                                                 const float* __restrict__ var,
                                                 const float* __restrict__ x,
                                                 float* __restrict__ out) {
    const int t  = threadIdx.x;
    const int b  = blockIdx.z;
    const int ob = blockIdx.y * 128;
    const int nb = blockIdx.x * 128;
    const int lane = t & 63, wave = t >> 6;
    const int wo = (wave >> 1) * 64, wn = (wave & 1) * 64;

    const int am = lane & 15, ak = lane >> 4;
    const unsigned short* ap0 = wbf + (size_t)(ob + wo + am) * 512 + ak * 8;
    const unsigned short* bp0 = att_f +
        (((size_t)b * 64 + ak) * HW + nb + wn + am) * 8;

    f32x4 acc[4][4];
#pragma unroll
    for (int s = 0; s < 4; s++)
#pragma unroll
        for (int u = 0; u < 4; u++) acc[s][u] = (f32x4){0.f, 0.f, 0.f, 0.f};

    for (int kb = 0; kb < 512; kb += 32) {
        short8 af[4], bf[4];
#pragma unroll
        for (int s = 0; s < 4; s++)
            af[s] = *(const short8*)(ap0 + (size_t)s * 16 * 512 + kb);
#pragma unroll
        for (int u = 0; u < 4; u++)
            bf[u] = *(const short8*)(bp0 + ((size_t)(kb >> 3) * HW + u * 16) * 8);
#pragma unroll
        for (int s = 0; s < 4; s++)
#pragma unroll
            for (int u = 0; u < 4; u++)
                acc[s][u] = __builtin_amdgcn_mfma_f32_16x16x32_bf16(af[s], bf[u], acc[s][u], 0, 0, 0);
    }

#pragma unroll
    for (int s = 0; s < 4; s++) {
        const int o_base = ob + wo + s * 16 + (lane >> 4) * 4;
#pragma unroll
        for (int r = 0; r < 4; r++) {
            const int o = o_base + r;
            const float inv = gamma[o] * rsqrtf(var[o] + BN_EPS);
            const float sh  = beta[o] - mean[o] * inv;
#pragma unroll
            for (int u = 0; u < 4; u++) {
                const int n = nb + wn + u * 16 + (lane & 15);
                const size_t idx = ((size_t)b * 256 + o) * HW + n;
                out[idx] = x[idx] + acc[s][u][r] * inv + sh;
            }
        }
    }
}

extern "C" void kernel_launch(void* const* d_in, const int* in_sizes, int n_in,
                              void* d_out, int out_size, void* d_ws, size_t ws_size,
                              hipStream_t stream) {
    const float* x      = (const float*)d_in[0];
    const float* w_qkv  = (const float*)d_in[1];
    const float* w_dw   = (const float*)d_in[2];
    const float* w_pw   = (const float*)d_in[3];
    const float* w_proj = (const float*)d_in[4];
    const float* gamma  = (const float*)d_in[5];
    const float* beta   = (const float*)d_in[6];
    const float* mean   = (const float*)d_in[7];
    const float* var    = (const float*)d_in[8];
    float* out = (float*)d_out;

    unsigned short* qkv  = (unsigned short*)d_ws;      // 25165824 shorts
    unsigned short* agg  = qkv + (size_t)25165824;     // 25165824 shorts
    unsigned short* attf = agg + (size_t)25165824;     // 16777216 shorts
    unsigned short* wbf  = attf + (size_t)16777216;    // 131072 shorts
    float* kvb = (float*)(wbf + (size_t)131072);       // 36864 floats
    float* kvpart = (float*)attf;                      // 16*36864 f32, transient
    unsigned short* wqbf = attf + (size_t)4194304;     // 196608 shorts, transient
    unsigned short* xt   = agg;                        // 8388608 shorts, transient
                                                       // (agg written later by dw_agg)

    prep_w  <<<dim3(128),       256, 0, stream>>>(w_proj, wbf);
    prep_wq <<<dim3(192),       256, 0, stream>>>(w_qkv, wqbf);
    prep_xt <<<dim3(64, 4, 8),  256, 0, stream>>>(x, xt);
    qkv_gemm<<<dim3(32, 6, 8),  256, 0, stream>>>(xt, wqbf, qkv);
    dw_agg  <<<dim3(4, 96, 8),  256, 0, stream>>>(qkv, w_dw, w_pw, agg);
    kv_pass <<<dim3(8, 8, 16),  256, 0, stream>>>(qkv, agg, kvpart);
    kv_red  <<<dim3(144),       256, 0, stream>>>(kvpart, kvb);
    att_pass<<<dim3(2, 64, 8),  256, 0, stream>>>(qkv, agg, kvb, attf);
    proj_gemm<<<dim3(32, 2, 8), 256, 0, stream>>>(wbf, attf,
                                                  gamma, beta, mean, var, x, out);
}

// Round 15
// 219.974 us; speedup vs baseline: 1.2555x; 1.0206x over previous
//
#include <hip/hip_runtime.h>
#include <hip/hip_bf16.h>

// LiteMLA: B=8, C=256, H=W=64, N=HW=4096, td=256, d=8, heads=64
// ws: qkv bf16 (8,768,4096) | agg bf16 (8,768,4096) | att_f bf16 (8,64,4096,8)
//     | w_projbf bf16 (256,512) | kvb f32 (8,64,72)
// Overlays (stream-order safe):
//   attf region: kvpart (16 x 36864 f32) at +0 ; wqbf (768x256 bf16) at +4194304
//   agg region:  xT bf16 [b][4096][256] at +0 (consumed by qkv_gemm BEFORE
//                dw_agg writes agg)
// Pipeline: prep_wb (merged w converts), prep_xt, qkv_gemm (vector LDS +
//           T14 issue-early staging), dw_agg (DPP halo + fill prefetch +
//           ch-unroll 2), kv_pass (MFMA), kv_red, att_pass, proj_gemm

#define HW 4096
#define ATT_EPS 1e-15f
#define BN_EPS 1e-6f

typedef __attribute__((ext_vector_type(8))) short short8;
typedef __attribute__((ext_vector_type(4))) short short4v;
typedef __attribute__((ext_vector_type(4))) float f32x4;
typedef __attribute__((ext_vector_type(2))) float f32x2;
typedef __attribute__((ext_vector_type(8))) unsigned short u16x8;
typedef __attribute__((ext_vector_type(4))) unsigned short u16x4;

static __device__ inline short f2bf(float f) {
    union { float f; unsigned u; } v; v.f = f;
    unsigned r = v.u + 0x7fff + ((v.u >> 16) & 1);   // RNE, finite inputs
    return (short)(r >> 16);
}
static __device__ inline float bf2f(unsigned short u) {
    union { unsigned u; float f; } v; v.u = (unsigned)u << 16; return v.f;
}

// DPP 16-lane row shifts (VALU, not LDS). bound_ctrl=1 -> row-edge lanes get 0,
// which coincides exactly with the image x-boundary zero-padding.
static __device__ inline float dpp_shr1(float x) {      // lane i <- lane i-1
    int i = __builtin_bit_cast(int, x);
    int r = __builtin_amdgcn_update_dpp(0, i, 0x111, 0xF, 0xF, true);
    return __builtin_bit_cast(float, r);
}
static __device__ inline float dpp_shl1(float x) {      // lane i <- lane i+1
    int i = __builtin_bit_cast(int, x);
    int r = __builtin_amdgcn_update_dpp(0, i, 0x101, 0xF, 0xF, true);
    return __builtin_bit_cast(float, r);
}

// ---------------- K0: w_proj + w_qkv f32 -> bf16 (merged, one launch) --------
__global__ __launch_bounds__(256) void prep_wb(const float* __restrict__ wproj,
                                               const float* __restrict__ wqkv,
                                               unsigned short* __restrict__ wbf,
                                               unsigned short* __restrict__ wqbf) {
    const int bid = blockIdx.x;
    const float* src;
    unsigned short* dst;
    int i;
    if (bid < 128) { src = wproj; dst = wbf;  i = (bid * 256 + threadIdx.x) * 4; }
    else           { src = wqkv;  dst = wqbf; i = ((bid - 128) * 256 + threadIdx.x) * 4; }
    float4 v = *(const float4*)&src[i];
    u16x4 r = {(unsigned short)f2bf(v.x), (unsigned short)f2bf(v.y),
               (unsigned short)f2bf(v.z), (unsigned short)f2bf(v.w)};
    *(u16x4*)&dst[i] = r;
}

// ---------------- K0c: x f32 [b][c][n] -> xT bf16 [b][n][c] ------------------
__global__ __launch_bounds__(256) void prep_xt(const float* __restrict__ x,
                                               unsigned short* __restrict__ xt) {
    __shared__ unsigned short tl[64][72];   // pitch 144B (16B-aligned rows)
    const int b = blockIdx.z;
    const int c0 = blockIdx.y * 64, n0 = blockIdx.x * 64;
    const int t = threadIdx.x;
    const int nq = t & 15, cl = t >> 4;     // n-quad, c-local base
#pragma unroll
    for (int p = 0; p < 4; p++) {
        const int c = cl + p * 16;
        float4 v = *(const float4*)&x[((size_t)b * 256 + c0 + c) * HW + n0 + nq * 4];
        tl[nq * 4 + 0][c] = (unsigned short)f2bf(v.x);
        tl[nq * 4 + 1][c] = (unsigned short)f2bf(v.y);
        tl[nq * 4 + 2][c] = (unsigned short)f2bf(v.z);
        tl[nq * 4 + 3][c] = (unsigned short)f2bf(v.w);
    }
    __syncthreads();
#pragma unroll
    for (int k = 0; k < 2; k++) {
        const int slot = t + 256 * k;           // 512 slots = 64n x 8 octets
        const int nl = slot >> 3, oct = slot & 7;
        u16x8 v = *(const u16x8*)&tl[nl][oct * 8];
        *(u16x8*)&xt[((size_t)b * 4096 + n0 + nl) * 256 + c0 + oct * 8] = v;
    }
}

// ---------------- K1: qkv = W(768x256) @ X — vector LDS + T14 split ----------
// R13-verified structure; NEW: staging loads issue during the PREVIOUS step's
// MFMA phase (issue-early / ds_write-late) so L2 latency hides under compute
// instead of sitting between the barriers (T14, guide §6 G15).
__global__ __launch_bounds__(256) void qkv_gemm(const unsigned short* __restrict__ xt,
                                                const unsigned short* __restrict__ wqbf,
                                                unsigned short* __restrict__ qkv) {
    __shared__ unsigned short A_l[128 * 40];
    __shared__ unsigned short B_l[128 * 40];
    const int t  = threadIdx.x;
    const int b  = blockIdx.z;
    const int ob = blockIdx.y * 128;
    const int nb = blockIdx.x * 128;
    const int lane = t & 63, wave = t >> 6;
    const int wo = (wave >> 1) * 64, wn = (wave & 1) * 64;
    const int am = lane & 15, ak = lane >> 4;

    const int r0 = t >> 2, c0 = t & 3;
    const unsigned short* asrc = wqbf + (size_t)(ob + r0) * 256 + c0 * 8;
    const unsigned short* bsrc = xt + ((size_t)b * 4096 + nb + r0) * 256 + c0 * 8;

    f32x4 acc[4][4];
#pragma unroll
    for (int s = 0; s < 4; s++)
#pragma unroll
        for (int u = 0; u < 4; u++) acc[s][u] = (f32x4){0.f, 0.f, 0.f, 0.f};

    u16x8 pa0, pa1, pb0, pb1;
#define QFETCH(KB)                                                             \
    {                                                                          \
        pa0 = *(const u16x8*)(asrc + (KB));                                    \
        pa1 = *(const u16x8*)(asrc + (size_t)64 * 256 + (KB));                 \
        pb0 = *(const u16x8*)(bsrc + (KB));                                    \
        pb1 = *(const u16x8*)(bsrc + (size_t)64 * 256 + (KB));                 \
    }

    QFETCH(0)
    for (int kb = 0; kb < 256; kb += 32) {
        __syncthreads();                 // prev-iter frag reads complete
        *(u16x8*)&A_l[r0 * 40 + c0 * 8]        = pa0;
        *(u16x8*)&A_l[(r0 + 64) * 40 + c0 * 8] = pa1;
        *(u16x8*)&B_l[r0 * 40 + c0 * 8]        = pb0;
        *(u16x8*)&B_l[(r0 + 64) * 40 + c0 * 8] = pb1;
        __syncthreads();

        if (kb + 32 < 256) QFETCH(kb + 32)   // issue-early: hides under MFMA

        short8 af[4], bf[4];
#pragma unroll
        for (int s = 0; s < 4; s++)
            af[s] = *(const short8*)&A_l[(wo + s * 16 + am) * 40 + ak * 8];
#pragma unroll
        for (int u = 0; u < 4; u++)
            bf[u] = *(const short8*)&B_l[(wn + u * 16 + am) * 40 + ak * 8];
#pragma unroll
        for (int s = 0; s < 4; s++)
#pragma unroll
            for (int u = 0; u < 4; u++)
                acc[s][u] = __builtin_amdgcn_mfma_f32_16x16x32_bf16(af[s], bf[u], acc[s][u], 0, 0, 0);
    }
#undef QFETCH

#pragma unroll
    for (int s = 0; s < 4; s++)
#pragma unroll
        for (int u = 0; u < 4; u++)
#pragma unroll
            for (int r = 0; r < 4; r++) {
                const int o = ob + wo + s * 16 + (lane >> 4) * 4 + r;
                const int nn = nb + wn + u * 16 + (lane & 15);
                qkv[((size_t)b * 768 + o) * HW + nn] = (unsigned short)f2bf(acc[s][u][r]);
            }
}

// ---------------- K2: fused dw5x5 + pw8x8, DPP halo + fill prefetch ----------
// R14: LDS reads down 3x but dur barely moved -> latency/sync-bound at 42% occ.
// NEW: (a) half-1 fill loads issue during half-0 compute (T14 split) so HBM/L2
// latency hides under FMA; (b) ch loop unroll 2 for ILP (VGPR 40 -> ~80,
// still 128-class; wk SGPR live 50 + pw 16, within budget).
__global__ __launch_bounds__(256, 4) void dw_agg(const unsigned short* __restrict__ qkv,
                                                 const float* __restrict__ wdw,
                                                 const float* __restrict__ wpw,
                                                 unsigned short* __restrict__ agg) {
    __shared__ float tile[4 * 20 * 64];     // 20 KB
    const int b = blockIdx.z, g = blockIdx.y;
    const int y0 = blockIdx.x * 16;
    const int t = threadIdx.x;
    const int tx = t & 15, ty = t >> 4;     // col-quad, output row

    const float* wkg = wdw + g * 8 * 25;    // block-uniform -> scalar loads
    const float* pwg = wpw + g * 64;        // block-uniform -> scalar loads

    float out[8][4];
#pragma unroll
    for (int o = 0; o < 8; o++)
#pragma unroll
        for (int j = 0; j < 4; j++) out[o][j] = 0.f;

    u16x8 pf0, pf1, pf2;
#define DWFETCH(HALF)                                                          \
    {                                                                          \
        _Pragma("unroll")                                                      \
        for (int k = 0; k < 3; k++) {                                          \
            const int i = t + 256 * k;                                         \
            u16x8 v = {0, 0, 0, 0, 0, 0, 0, 0};                                \
            if (i < 640) {                                                     \
                const int c8 = i & 7, rr = (i >> 3) % 20, ch = i / 160;        \
                const int y = y0 - 2 + rr;                                     \
                if (y >= 0 && y < 64)                                          \
                    v = *(const u16x8*)&qkv[((size_t)(b * 768 + g * 8 + (HALF) * 4 + ch)) * HW + y * 64 + c8 * 8]; \
            }                                                                  \
            if (k == 0) pf0 = v; else if (k == 1) pf1 = v; else pf2 = v;       \
        }                                                                      \
    }

    DWFETCH(0)
#pragma unroll 1
    for (int half = 0; half < 2; half++) {
        if (half) __syncthreads();          // all reads of prev half done
        // write phase: cvt + vector stores from prefetched regs
#pragma unroll
        for (int k = 0; k < 3; k++) {
            const int i = t + 256 * k;
            if (i < 640) {
                u16x8 v = (k == 0) ? pf0 : (k == 1) ? pf1 : pf2;
                f32x4 lo = {bf2f(v[0]), bf2f(v[1]), bf2f(v[2]), bf2f(v[3])};
                f32x4 hi = {bf2f(v[4]), bf2f(v[5]), bf2f(v[6]), bf2f(v[7])};
                *(f32x4*)&tile[i * 8]     = lo;
                *(f32x4*)&tile[i * 8 + 4] = hi;
            }
        }
        __syncthreads();
        if (half == 0) DWFETCH(1)           // issue-early: hides under compute

#pragma unroll 2
        for (int ch4 = 0; ch4 < 4; ch4++) {
            const int ch = half * 4 + ch4;
            const float* wkc = wkg + ch * 25;    // uniform -> SGPR
            float a0 = 0.f, a1 = 0.f, a2 = 0.f, a3 = 0.f;
#pragma unroll
            for (int dy = 0; dy < 5; dy++) {
                const int off = ch4 * 1280 + (ty + dy) * 64 + tx * 4;
                f32x4 C = *(const f32x4*)&tile[off];    // the ONLY LDS read
                float win[8];
                win[0] = dpp_shr1(C[2]);    // lane-1's C[2]; 0 at tx==0
                win[1] = dpp_shr1(C[3]);
                win[2] = C[0]; win[3] = C[1];
                win[4] = C[2]; win[5] = C[3];
                win[6] = dpp_shl1(C[0]);    // lane+1's C[0]; 0 at tx==15
                win[7] = dpp_shl1(C[1]);
#pragma unroll
                for (int dx = 0; dx < 5; dx++) {
                    const float wv = wkc[dy * 5 + dx];      // SGPR operand
                    a0 += wv * win[dx + 0];
                    a1 += wv * win[dx + 1];
                    a2 += wv * win[dx + 2];
                    a3 += wv * win[dx + 3];
                }
            }
#pragma unroll
            for (int o = 0; o < 8; o++) {
                const float wv = pwg[o * 8 + ch];           // SGPR operand
                out[o][0] += wv * a0; out[o][1] += wv * a1;
                out[o][2] += wv * a2; out[o][3] += wv * a3;
            }
        }
    }
#undef DWFETCH

#pragma unroll
    for (int o = 0; o < 8; o++) {
        u16x4 rv = {(unsigned short)f2bf(out[o][0]), (unsigned short)f2bf(out[o][1]),
                    (unsigned short)f2bf(out[o][2]), (unsigned short)f2bf(out[o][3])};
        *(u16x4*)&agg[((size_t)(b * 768 + g * 8 + o)) * HW + (y0 + ty) * 64 + tx * 4] = rv;
    }
}

// ---------------- K3: kv partials via MFMA (head-pair per wave) --------------
__global__ __launch_bounds__(256) void kv_pass(const unsigned short* __restrict__ qkv,
                                               const unsigned short* __restrict__ agg,
                                               float* __restrict__ kvpart) {
    const int t = threadIdx.x;
    const int w = t >> 6, lane = t & 63;
    const int hp = blockIdx.x * 4 + w;          // head-pair 0..31
    const int b = blockIdx.y, c = blockIdx.z;   // batch, n-chunk
    const int h0 = hp * 2, h1 = h0 + 1;         // same buf half always
    const unsigned short* buf = (h0 < 32) ? qkv : agg;
    const int cb0 = (h0 & 31) * 24, cb1 = (h1 & 31) * 24;

    const int row = lane & 15, kgrp = lane >> 4;
    const int n0 = c * 256 + kgrp * 8;

    const int chA = (row < 8) ? (cb0 + 8 + row) : (cb1 + row);
    const unsigned short* ap = buf + ((size_t)b * 768 + chA) * HW + n0;

    const bool bload = (row < 8);
    const unsigned short* bp0 = buf + ((size_t)b * 768 + cb0 + 16 + (row & 7)) * HW + n0;
    const unsigned short* bp1 = buf + ((size_t)b * 768 + cb1 + 16 + (row & 7)) * HW + n0;
    const short cfill = (row == 8) ? (short)0x3F80 : (short)0;   // bf16 1.0
    const short8 bconst = {cfill, cfill, cfill, cfill, cfill, cfill, cfill, cfill};

    f32x4 acc0 = {0.f, 0.f, 0.f, 0.f};
    f32x4 acc1 = {0.f, 0.f, 0.f, 0.f};

#pragma unroll
    for (int i = 0; i < 8; i++) {
        u16x8 av = *(const u16x8*)(ap + i * 32);
        short8 b0 = bload ? *(const short8*)(bp0 + i * 32) : bconst;
        short8 b1 = bload ? *(const short8*)(bp1 + i * 32) : bconst;
        short8 ar;
#pragma unroll
        for (int j = 0; j < 8; j++)
            ar[j] = (short)((av[j] & 0x8000) ? 0 : av[j]);    // relu on bf16 bits
        acc0 = __builtin_amdgcn_mfma_f32_16x16x32_bf16(ar, b0, acc0, 0, 0, 0);
        acc1 = __builtin_amdgcn_mfma_f32_16x16x32_bf16(ar, b1, acc1, 0, 0, 0);
    }

    if (row <= 8) {
        float* kp;
        f32x4 a;
        int dbase;
        if (kgrp < 2) {
            kp = kvpart + (size_t)c * 36864 + (size_t)(b * 64 + h0) * 72;
            a = acc0; dbase = kgrp * 4;
        } else {
            kp = kvpart + (size_t)c * 36864 + (size_t)(b * 64 + h1) * 72;
            a = acc1; dbase = (kgrp - 2) * 4;
        }
#pragma unroll
        for (int r = 0; r < 4; r++)
            kp[(dbase + r) * 9 + row] = a[r];
    }
}

// ---------------- K3b: sum the 16 kv partial chunks --------------------------
__global__ __launch_bounds__(256) void kv_red(const float* __restrict__ kvpart,
                                              float* __restrict__ kvout) {
    const int i = blockIdx.x * 256 + threadIdx.x;   // 144 blocks x 256 = 36864
    float s = 0.f;
#pragma unroll
    for (int c = 0; c < 16; c++) s += kvpart[(size_t)c * 36864 + i];
    kvout[i] = s;
}

// ---------------- K4: att -> att_f[b][h][n][8] (B-fragment-ready bf16) -------
__global__ __launch_bounds__(256) void att_pass(const unsigned short* __restrict__ qkv,
                                                const unsigned short* __restrict__ agg,
                                                const float* __restrict__ kvbuf,
                                                unsigned short* __restrict__ att_f) {
    const int h = blockIdx.y, b = blockIdx.z;
    const int t = threadIdx.x;
    const float* kvp = kvbuf + ((size_t)(b * 64 + h)) * 72;   // block-uniform

    float kvr[72];
#pragma unroll
    for (int i = 0; i < 18; i++) {
        f32x4 v = *(const f32x4*)&kvp[i * 4];
        kvr[i * 4 + 0] = v[0]; kvr[i * 4 + 1] = v[1];
        kvr[i * 4 + 2] = v[2]; kvr[i * 4 + 3] = v[3];
    }

    const unsigned short* buf = (h < 32) ? qkv : agg;
    const int cbase = (h & 31) * 24;
    const int n0 = (blockIdx.x * 256 + t) * 8;
    const unsigned short* qp = buf + ((size_t)b * 768 + cbase) * HW + n0;

    float q[8][8];
#pragma unroll
    for (int d = 0; d < 8; d++) {
        u16x8 v = *(const u16x8*)&qp[(size_t)d * HW];
#pragma unroll
        for (int j = 0; j < 8; j++) q[d][j] = fmaxf(bf2f(v[j]), 0.f);
    }

    unsigned short* op = att_f + (((size_t)(b * 64 + h)) * HW + n0) * 8;
#pragma unroll
    for (int j = 0; j < 8; j++) {
        float num[9];
#pragma unroll
        for (int e = 0; e < 9; e++) num[e] = 0.f;
#pragma unroll
        for (int d = 0; d < 8; d++) {
            const float qv = q[d][j];
#pragma unroll
            for (int e = 0; e < 9; e++) num[e] += qv * kvr[d * 9 + e];
        }
        const float rden = 1.f / (num[8] + ATT_EPS);
        u16x8 r;
#pragma unroll
        for (int e = 0; e < 8; e++) r[e] = (unsigned short)f2bf(num[e] * rden);
        *(u16x8*)&op[j * 8] = r;
    }
}

// ---------------- K5: p = Wp @ att, BN, +x — LDS-free direct-frag MFMA -------
__global__ __launch_bounds__(256) void proj_gemm(const unsigned short* __restrict__ wbf,
                                                 const unsigned short* __restrict__ att_f,
                                                 const float* __restrict__ gamma,
                                                 const float* __restrict__ beta,
                                                 const float* __restrict__ mean,
                                                 const float* __restrict__ var,
                                                 const float* __restrict__ x,
                                                 float* __restrict__ out) {
    const int t  = threadIdx.x;
    const int b  = blockIdx.z;
    const int ob = blockIdx.y * 128;
    const int nb = blockIdx.x * 128;
    const int lane = t & 63, wave = t >> 6;
    const int wo = (wave >> 1) * 64, wn = (wave & 1) * 64;

    const int am = lane & 15, ak = lane >> 4;
    const unsigned short* ap0 = wbf + (size_t)(ob + wo + am) * 512 + ak * 8;
    const unsigned short* bp0 = att_f +
        (((size_t)b * 64 + ak) * HW + nb + wn + am) * 8;

    f32x4 acc[4][4];
#pragma unroll
    for (int s = 0; s < 4; s++)
#pragma unroll
        for (int u = 0; u < 4; u++) acc[s][u] = (f32x4){0.f, 0.f, 0.f, 0.f};

    for (int kb = 0; kb < 512; kb += 32) {
        short8 af[4], bf[4];
#pragma unroll
        for (int s = 0; s < 4; s++)
            af[s] = *(const short8*)(ap0 + (size_t)s * 16 * 512 + kb);
#pragma unroll
        for (int u = 0; u < 4; u++)
            bf[u] = *(const short8*)(bp0 + ((size_t)(kb >> 3) * HW + u * 16) * 8);
#pragma unroll
        for (int s = 0; s < 4; s++)
#pragma unroll
            for (int u = 0; u < 4; u++)
                acc[s][u] = __builtin_amdgcn_mfma_f32_16x16x32_bf16(af[s], bf[u], acc[s][u], 0, 0, 0);
    }

#pragma unroll
    for (int s = 0; s < 4; s++) {
        const int o_base = ob + wo + s * 16 + (lane >> 4) * 4;
#pragma unroll
        for (int r = 0; r < 4; r++) {
            const int o = o_base + r;
            const float inv = gamma[o] * rsqrtf(var[o] + BN_EPS);
            const float sh  = beta[o] - mean[o] * inv;
#pragma unroll
            for (int u = 0; u < 4; u++) {
                const int n = nb + wn + u * 16 + (lane & 15);
                const size_t idx = ((size_t)b * 256 + o) * HW + n;
                out[idx] = x[idx] + acc[s][u][r] * inv + sh;
            }
        }
    }
}

extern "C" void kernel_launch(void* const* d_in, const int* in_sizes, int n_in,
                              void* d_out, int out_size, void* d_ws, size_t ws_size,
                              hipStream_t stream) {
    const float* x      = (const float*)d_in[0];
    const float* w_qkv  = (const float*)d_in[1];
    const float* w_dw   = (const float*)d_in[2];
    const float* w_pw   = (const float*)d_in[3];
    const float* w_proj = (const float*)d_in[4];
    const float* gamma  = (const float*)d_in[5];
    const float* beta   = (const float*)d_in[6];
    const float* mean   = (const float*)d_in[7];
    const float* var    = (const float*)d_in[8];
    float* out = (float*)d_out;

    unsigned short* qkv  = (unsigned short*)d_ws;      // 25165824 shorts
    unsigned short* agg  = qkv + (size_t)25165824;     // 25165824 shorts
    unsigned short* attf = agg + (size_t)25165824;     // 16777216 shorts
    unsigned short* wbf  = attf + (size_t)16777216;    // 131072 shorts
    float* kvb = (float*)(wbf + (size_t)131072);       // 36864 floats
    float* kvpart = (float*)attf;                      // 16*36864 f32, transient
    unsigned short* wqbf = attf + (size_t)4194304;     // 196608 shorts, transient
    unsigned short* xt   = agg;                        // 8388608 shorts, transient
                                                       // (agg written later by dw_agg)

    prep_wb <<<dim3(320),       256, 0, stream>>>(w_proj, w_qkv, wbf, wqbf);
    prep_xt <<<dim3(64, 4, 8),  256, 0, stream>>>(x, xt);
    qkv_gemm<<<dim3(32, 6, 8),  256, 0, stream>>>(xt, wqbf, qkv);
    dw_agg  <<<dim3(4, 96, 8),  256, 0, stream>>>(qkv, w_dw, w_pw, agg);
    kv_pass <<<dim3(8, 8, 16),  256, 0, stream>>>(qkv, agg, kvpart);
    kv_red  <<<dim3(144),       256, 0, stream>>>(kvpart, kvb);
    att_pass<<<dim3(2, 64, 8),  256, 0, stream>>>(qkv, agg, kvb, attf);
    proj_gemm<<<dim3(32, 2, 8), 256, 0, stream>>>(wbf, attf,
                                                  gamma, beta, mean, var, x, out);
}

// Round 16
// 218.334 us; speedup vs baseline: 1.2649x; 1.0075x over previous
//
#include <hip/hip_runtime.h>
#include <hip/hip_bf16.h>

// LiteMLA: B=8, C=256, H=W=64, N=HW=4096, td=256, d=8, heads=64
// ws: qkv bf16 (8,768,4096) | agg bf16 (8,768,4096) | att_f bf16 (8,64,4096,8)
//     | w_projbf bf16 (256,512) | kvb f32 (8,64,72)
// Overlays (stream-order safe):
//   attf region: kvpart (16 x 36864 f32) at +0 ; wqbf (768x256 bf16) at +4194304
//   agg region:  xT bf16 [b][4096][256] at +0 (consumed by qkv_gemm BEFORE
//                dw_agg writes agg)
// Pipeline: prep_wb, prep_xt, qkv_gemm (vector LDS + T14), dw_agg (DPP halo +
//           fill prefetch), kv_pass (MFMA), kv_red, att_pass,
//           proj_gemm (NEW: 64x128 tile, barrier-staged vector LDS + T14 —
//           R13's proven cure for the LDS-free latency chain, 4 blocks/CU)

#define HW 4096
#define ATT_EPS 1e-15f
#define BN_EPS 1e-6f

typedef __attribute__((ext_vector_type(8))) short short8;
typedef __attribute__((ext_vector_type(4))) short short4v;
typedef __attribute__((ext_vector_type(4))) float f32x4;
typedef __attribute__((ext_vector_type(2))) float f32x2;
typedef __attribute__((ext_vector_type(8))) unsigned short u16x8;
typedef __attribute__((ext_vector_type(4))) unsigned short u16x4;

static __device__ inline short f2bf(float f) {
    union { float f; unsigned u; } v; v.f = f;
    unsigned r = v.u + 0x7fff + ((v.u >> 16) & 1);   // RNE, finite inputs
    return (short)(r >> 16);
}
static __device__ inline float bf2f(unsigned short u) {
    union { unsigned u; float f; } v; v.u = (unsigned)u << 16; return v.f;
}

// DPP 16-lane row shifts (VALU, not LDS). bound_ctrl=1 -> row-edge lanes get 0,
// which coincides exactly with the image x-boundary zero-padding.
static __device__ inline float dpp_shr1(float x) {      // lane i <- lane i-1
    int i = __builtin_bit_cast(int, x);
    int r = __builtin_amdgcn_update_dpp(0, i, 0x111, 0xF, 0xF, true);
    return __builtin_bit_cast(float, r);
}
static __device__ inline float dpp_shl1(float x) {      // lane i <- lane i+1
    int i = __builtin_bit_cast(int, x);
    int r = __builtin_amdgcn_update_dpp(0, i, 0x101, 0xF, 0xF, true);
    return __builtin_bit_cast(float, r);
}

// ---------------- K0: w_proj + w_qkv f32 -> bf16 (merged, one launch) --------
__global__ __launch_bounds__(256) void prep_wb(const float* __restrict__ wproj,
                                               const float* __restrict__ wqkv,
                                               unsigned short* __restrict__ wbf,
                                               unsigned short* __restrict__ wqbf) {
    const int bid = blockIdx.x;
    const float* src;
    unsigned short* dst;
    int i;
    if (bid < 128) { src = wproj; dst = wbf;  i = (bid * 256 + threadIdx.x) * 4; }
    else           { src = wqkv;  dst = wqbf; i = ((bid - 128) * 256 + threadIdx.x) * 4; }
    float4 v = *(const float4*)&src[i];
    u16x4 r = {(unsigned short)f2bf(v.x), (unsigned short)f2bf(v.y),
               (unsigned short)f2bf(v.z), (unsigned short)f2bf(v.w)};
    *(u16x4*)&dst[i] = r;
}

// ---------------- K0c: x f32 [b][c][n] -> xT bf16 [b][n][c] ------------------
__global__ __launch_bounds__(256) void prep_xt(const float* __restrict__ x,
                                               unsigned short* __restrict__ xt) {
    __shared__ unsigned short tl[64][72];   // pitch 144B (16B-aligned rows)
    const int b = blockIdx.z;
    const int c0 = blockIdx.y * 64, n0 = blockIdx.x * 64;
    const int t = threadIdx.x;
    const int nq = t & 15, cl = t >> 4;     // n-quad, c-local base
#pragma unroll
    for (int p = 0; p < 4; p++) {
        const int c = cl + p * 16;
        float4 v = *(const float4*)&x[((size_t)b * 256 + c0 + c) * HW + n0 + nq * 4];
        tl[nq * 4 + 0][c] = (unsigned short)f2bf(v.x);
        tl[nq * 4 + 1][c] = (unsigned short)f2bf(v.y);
        tl[nq * 4 + 2][c] = (unsigned short)f2bf(v.z);
        tl[nq * 4 + 3][c] = (unsigned short)f2bf(v.w);
    }
    __syncthreads();
#pragma unroll
    for (int k = 0; k < 2; k++) {
        const int slot = t + 256 * k;           // 512 slots = 64n x 8 octets
        const int nl = slot >> 3, oct = slot & 7;
        u16x8 v = *(const u16x8*)&tl[nl][oct * 8];
        *(u16x8*)&xt[((size_t)b * 4096 + n0 + nl) * 256 + c0 + oct * 8] = v;
    }
}

// ---------------- K1: qkv = W(768x256) @ X — vector LDS + T14 split ----------
__global__ __launch_bounds__(256) void qkv_gemm(const unsigned short* __restrict__ xt,
                                                const unsigned short* __restrict__ wqbf,
                                                unsigned short* __restrict__ qkv) {
    __shared__ unsigned short A_l[128 * 40];
    __shared__ unsigned short B_l[128 * 40];
    const int t  = threadIdx.x;
    const int b  = blockIdx.z;
    const int ob = blockIdx.y * 128;
    const int nb = blockIdx.x * 128;
    const int lane = t & 63, wave = t >> 6;
    const int wo = (wave >> 1) * 64, wn = (wave & 1) * 64;
    const int am = lane & 15, ak = lane >> 4;

    const int r0 = t >> 2, c0 = t & 3;
    const unsigned short* asrc = wqbf + (size_t)(ob + r0) * 256 + c0 * 8;
    const unsigned short* bsrc = xt + ((size_t)b * 4096 + nb + r0) * 256 + c0 * 8;

    f32x4 acc[4][4];
#pragma unroll
    for (int s = 0; s < 4; s++)
#pragma unroll
        for (int u = 0; u < 4; u++) acc[s][u] = (f32x4){0.f, 0.f, 0.f, 0.f};

    u16x8 pa0, pa1, pb0, pb1;
#define QFETCH(KB)                                                             \
    {                                                                          \
        pa0 = *(const u16x8*)(asrc + (KB));                                    \
        pa1 = *(const u16x8*)(asrc + (size_t)64 * 256 + (KB));                 \
        pb0 = *(const u16x8*)(bsrc + (KB));                                    \
        pb1 = *(const u16x8*)(bsrc + (size_t)64 * 256 + (KB));                 \
    }

    QFETCH(0)
    for (int kb = 0; kb < 256; kb += 32) {
        __syncthreads();                 // prev-iter frag reads complete
        *(u16x8*)&A_l[r0 * 40 + c0 * 8]        = pa0;
        *(u16x8*)&A_l[(r0 + 64) * 40 + c0 * 8] = pa1;
        *(u16x8*)&B_l[r0 * 40 + c0 * 8]        = pb0;
        *(u16x8*)&B_l[(r0 + 64) * 40 + c0 * 8] = pb1;
        __syncthreads();

        if (kb + 32 < 256) QFETCH(kb + 32)   // issue-early: hides under MFMA

        short8 af[4], bf[4];
#pragma unroll
        for (int s = 0; s < 4; s++)
            af[s] = *(const short8*)&A_l[(wo + s * 16 + am) * 40 + ak * 8];
#pragma unroll
        for (int u = 0; u < 4; u++)
            bf[u] = *(const short8*)&B_l[(wn + u * 16 + am) * 40 + ak * 8];
#pragma unroll
        for (int s = 0; s < 4; s++)
#pragma unroll
            for (int u = 0; u < 4; u++)
                acc[s][u] = __builtin_amdgcn_mfma_f32_16x16x32_bf16(af[s], bf[u], acc[s][u], 0, 0, 0);
    }
#undef QFETCH

#pragma unroll
    for (int s = 0; s < 4; s++)
#pragma unroll
        for (int u = 0; u < 4; u++)
#pragma unroll
            for (int r = 0; r < 4; r++) {
                const int o = ob + wo + s * 16 + (lane >> 4) * 4 + r;
                const int nn = nb + wn + u * 16 + (lane & 15);
                qkv[((size_t)b * 768 + o) * HW + nn] = (unsigned short)f2bf(acc[s][u][r]);
            }
}

// ---------------- K2: fused dw5x5 + pw8x8, DPP halo + fill prefetch ----------
__global__ __launch_bounds__(256, 4) void dw_agg(const unsigned short* __restrict__ qkv,
                                                 const float* __restrict__ wdw,
                                                 const float* __restrict__ wpw,
                                                 unsigned short* __restrict__ agg) {
    __shared__ float tile[4 * 20 * 64];     // 20 KB
    const int b = blockIdx.z, g = blockIdx.y;
    const int y0 = blockIdx.x * 16;
    const int t = threadIdx.x;
    const int tx = t & 15, ty = t >> 4;     // col-quad, output row

    const float* wkg = wdw + g * 8 * 25;    // block-uniform -> scalar loads
    const float* pwg = wpw + g * 64;        // block-uniform -> scalar loads

    float out[8][4];
#pragma unroll
    for (int o = 0; o < 8; o++)
#pragma unroll
        for (int j = 0; j < 4; j++) out[o][j] = 0.f;

    u16x8 pf0, pf1, pf2;
#define DWFETCH(HALF)                                                          \
    {                                                                          \
        _Pragma("unroll")                                                      \
        for (int k = 0; k < 3; k++) {                                          \
            const int i = t + 256 * k;                                         \
            u16x8 v = {0, 0, 0, 0, 0, 0, 0, 0};                                \
            if (i < 640) {                                                     \
                const int c8 = i & 7, rr = (i >> 3) % 20, ch = i / 160;        \
                const int y = y0 - 2 + rr;                                     \
                if (y >= 0 && y < 64)                                          \
                    v = *(const u16x8*)&qkv[((size_t)(b * 768 + g * 8 + (HALF) * 4 + ch)) * HW + y * 64 + c8 * 8]; \
            }                                                                  \
            if (k == 0) pf0 = v; else if (k == 1) pf1 = v; else pf2 = v;       \
        }                                                                      \
    }

    DWFETCH(0)
#pragma unroll 1
    for (int half = 0; half < 2; half++) {
        if (half) __syncthreads();          // all reads of prev half done
#pragma unroll
        for (int k = 0; k < 3; k++) {
            const int i = t + 256 * k;
            if (i < 640) {
                u16x8 v = (k == 0) ? pf0 : (k == 1) ? pf1 : pf2;
                f32x4 lo = {bf2f(v[0]), bf2f(v[1]), bf2f(v[2]), bf2f(v[3])};
                f32x4 hi = {bf2f(v[4]), bf2f(v[5]), bf2f(v[6]), bf2f(v[7])};
                *(f32x4*)&tile[i * 8]     = lo;
                *(f32x4*)&tile[i * 8 + 4] = hi;
            }
        }
        __syncthreads();
        if (half == 0) DWFETCH(1)           // issue-early: hides under compute

#pragma unroll 2
        for (int ch4 = 0; ch4 < 4; ch4++) {
            const int ch = half * 4 + ch4;
            const float* wkc = wkg + ch * 25;    // uniform -> SGPR
            float a0 = 0.f, a1 = 0.f, a2 = 0.f, a3 = 0.f;
#pragma unroll
            for (int dy = 0; dy < 5; dy++) {
                const int off = ch4 * 1280 + (ty + dy) * 64 + tx * 4;
                f32x4 C = *(const f32x4*)&tile[off];    // the ONLY LDS read
                float win[8];
                win[0] = dpp_shr1(C[2]);    // lane-1's C[2]; 0 at tx==0
                win[1] = dpp_shr1(C[3]);
                win[2] = C[0]; win[3] = C[1];
                win[4] = C[2]; win[5] = C[3];
                win[6] = dpp_shl1(C[0]);    // lane+1's C[0]; 0 at tx==15
                win[7] = dpp_shl1(C[1]);
#pragma unroll
                for (int dx = 0; dx < 5; dx++) {
                    const float wv = wkc[dy * 5 + dx];      // SGPR operand
                    a0 += wv * win[dx + 0];
                    a1 += wv * win[dx + 1];
                    a2 += wv * win[dx + 2];
                    a3 += wv * win[dx + 3];
                }
            }
#pragma unroll
            for (int o = 0; o < 8; o++) {
                const float wv = pwg[o * 8 + ch];           // SGPR operand
                out[o][0] += wv * a0; out[o][1] += wv * a1;
                out[o][2] += wv * a2; out[o][3] += wv * a3;
            }
        }
    }
#undef DWFETCH

#pragma unroll
    for (int o = 0; o < 8; o++) {
        u16x4 rv = {(unsigned short)f2bf(out[o][0]), (unsigned short)f2bf(out[o][1]),
                    (unsigned short)f2bf(out[o][2]), (unsigned short)f2bf(out[o][3])};
        *(u16x4*)&agg[((size_t)(b * 768 + g * 8 + o)) * HW + (y0 + ty) * 64 + tx * 4] = rv;
    }
}

// ---------------- K3: kv partials via MFMA (head-pair per wave) --------------
__global__ __launch_bounds__(256) void kv_pass(const unsigned short* __restrict__ qkv,
                                               const unsigned short* __restrict__ agg,
                                               float* __restrict__ kvpart) {
    const int t = threadIdx.x;
    const int w = t >> 6, lane = t & 63;
    const int hp = blockIdx.x * 4 + w;          // head-pair 0..31
    const int b = blockIdx.y, c = blockIdx.z;   // batch, n-chunk
    const int h0 = hp * 2, h1 = h0 + 1;         // same buf half always
    const unsigned short* buf = (h0 < 32) ? qkv : agg;
    const int cb0 = (h0 & 31) * 24, cb1 = (h1 & 31) * 24;

    const int row = lane & 15, kgrp = lane >> 4;
    const int n0 = c * 256 + kgrp * 8;

    const int chA = (row < 8) ? (cb0 + 8 + row) : (cb1 + row);
    const unsigned short* ap = buf + ((size_t)b * 768 + chA) * HW + n0;

    const bool bload = (row < 8);
    const unsigned short* bp0 = buf + ((size_t)b * 768 + cb0 + 16 + (row & 7)) * HW + n0;
    const unsigned short* bp1 = buf + ((size_t)b * 768 + cb1 + 16 + (row & 7)) * HW + n0;
    const short cfill = (row == 8) ? (short)0x3F80 : (short)0;   // bf16 1.0
    const short8 bconst = {cfill, cfill, cfill, cfill, cfill, cfill, cfill, cfill};

    f32x4 acc0 = {0.f, 0.f, 0.f, 0.f};
    f32x4 acc1 = {0.f, 0.f, 0.f, 0.f};

#pragma unroll
    for (int i = 0; i < 8; i++) {
        u16x8 av = *(const u16x8*)(ap + i * 32);
        short8 b0 = bload ? *(const short8*)(bp0 + i * 32) : bconst;
        short8 b1 = bload ? *(const short8*)(bp1 + i * 32) : bconst;
        short8 ar;
#pragma unroll
        for (int j = 0; j < 8; j++)
            ar[j] = (short)((av[j] & 0x8000) ? 0 : av[j]);    // relu on bf16 bits
        acc0 = __builtin_amdgcn_mfma_f32_16x16x32_bf16(ar, b0, acc0, 0, 0, 0);
        acc1 = __builtin_amdgcn_mfma_f32_16x16x32_bf16(ar, b1, acc1, 0, 0, 0);
    }

    if (row <= 8) {
        float* kp;
        f32x4 a;
        int dbase;
        if (kgrp < 2) {
            kp = kvpart + (size_t)c * 36864 + (size_t)(b * 64 + h0) * 72;
            a = acc0; dbase = kgrp * 4;
        } else {
            kp = kvpart + (size_t)c * 36864 + (size_t)(b * 64 + h1) * 72;
            a = acc1; dbase = (kgrp - 2) * 4;
        }
#pragma unroll
        for (int r = 0; r < 4; r++)
            kp[(dbase + r) * 9 + row] = a[r];
    }
}

// ---------------- K3b: sum the 16 kv partial chunks --------------------------
__global__ __launch_bounds__(256) void kv_red(const float* __restrict__ kvpart,
                                              float* __restrict__ kvout) {
    const int i = blockIdx.x * 256 + threadIdx.x;   // 144 blocks x 256 = 36864
    float s = 0.f;
#pragma unroll
    for (int c = 0; c < 16; c++) s += kvpart[(size_t)c * 36864 + i];
    kvout[i] = s;
}

// ---------------- K4: att -> att_f[b][h][n][8] (B-fragment-ready bf16) -------
__global__ __launch_bounds__(256) void att_pass(const unsigned short* __restrict__ qkv,
                                                const unsigned short* __restrict__ agg,
                                                const float* __restrict__ kvbuf,
                                                unsigned short* __restrict__ att_f) {
    const int h = blockIdx.y, b = blockIdx.z;
    const int t = threadIdx.x;
    const float* kvp = kvbuf + ((size_t)(b * 64 + h)) * 72;   // block-uniform

    float kvr[72];
#pragma unroll
    for (int i = 0; i < 18; i++) {
        f32x4 v = *(const f32x4*)&kvp[i * 4];
        kvr[i * 4 + 0] = v[0]; kvr[i * 4 + 1] = v[1];
        kvr[i * 4 + 2] = v[2]; kvr[i * 4 + 3] = v[3];
    }

    const unsigned short* buf = (h < 32) ? qkv : agg;
    const int cbase = (h & 31) * 24;
    const int n0 = (blockIdx.x * 256 + t) * 8;
    const unsigned short* qp = buf + ((size_t)b * 768 + cbase) * HW + n0;

    float q[8][8];
#pragma unroll
    for (int d = 0; d < 8; d++) {
        u16x8 v = *(const u16x8*)&qp[(size_t)d * HW];
#pragma unroll
        for (int j = 0; j < 8; j++) q[d][j] = fmaxf(bf2f(v[j]), 0.f);
    }

    unsigned short* op = att_f + (((size_t)(b * 64 + h)) * HW + n0) * 8;
#pragma unroll
    for (int j = 0; j < 8; j++) {
        float num[9];
#pragma unroll
        for (int e = 0; e < 9; e++) num[e] = 0.f;
#pragma unroll
        for (int d = 0; d < 8; d++) {
            const float qv = q[d][j];
#pragma unroll
            for (int e = 0; e < 9; e++) num[e] += qv * kvr[d * 9 + e];
        }
        const float rden = 1.f / (num[8] + ATT_EPS);
        u16x8 r;
#pragma unroll
        for (int e = 0; e < 8; e++) r[e] = (unsigned short)f2bf(num[e] * rden);
        *(u16x8*)&op[j * 8] = r;
    }
}

// ---------------- K5: p = Wp @ att, BN, +x — staged vector LDS (64x128) ------
// R12/R13 lesson applied to proj: the LDS-free direct-frag loop at 2 blocks/CU
// is a latency chain. Now: 64x128 tile -> grid (32,4,8) = 1024 blocks =
// 4 blocks/CU; barrier-staged all-u16x8 LDS (A from wbf [o][k]; B from attf —
// one k-octet per load, h = k/8) + T14 issue-early prefetch. acc[4][2] =
// 32 AGPR (128-reg class). A 4x-redundancy is free (wbf L2-resident).
__global__ __launch_bounds__(256) void proj_gemm(const unsigned short* __restrict__ wbf,
                                                 const unsigned short* __restrict__ att_f,
                                                 const float* __restrict__ gamma,
                                                 const float* __restrict__ beta,
                                                 const float* __restrict__ mean,
                                                 const float* __restrict__ var,
                                                 const float* __restrict__ x,
                                                 float* __restrict__ out) {
    __shared__ unsigned short A_l[64 * 40];     // 5.1 KB
    __shared__ unsigned short B_l[128 * 40];    // 10.2 KB
    const int t  = threadIdx.x;
    const int b  = blockIdx.z;
    const int ob = blockIdx.y * 64;
    const int nb = blockIdx.x * 128;
    const int lane = t & 63, wave = t >> 6;
    const int wn = wave * 32;
    const int am = lane & 15, ak = lane >> 4;

    // staging: A 256 slots (64 rows x 4 octets), B 512 slots (128 n x 4 octets)
    const int srow = t >> 2, sc8 = t & 3;
    const unsigned short* asrc = wbf + (size_t)(ob + srow) * 512 + sc8 * 8;
    // B src: k-octet sc8 of step kb -> h = kb/8 + sc8; n = nb + srow (+64)
    const unsigned short* bbase = att_f + (size_t)b * 64 * HW * 8;

    f32x4 acc[4][2];
#pragma unroll
    for (int s = 0; s < 4; s++)
#pragma unroll
        for (int u = 0; u < 2; u++) acc[s][u] = (f32x4){0.f, 0.f, 0.f, 0.f};

    u16x8 pa, pb0, pb1;
#define PFETCH(KB)                                                             \
    {                                                                          \
        pa  = *(const u16x8*)(asrc + (KB));                                    \
        pb0 = *(const u16x8*)(bbase + (((size_t)((KB) >> 3) + sc8) * HW + nb + srow) * 8); \
        pb1 = *(const u16x8*)(bbase + (((size_t)((KB) >> 3) + sc8) * HW + nb + srow + 64) * 8); \
    }

    PFETCH(0)
    for (int kb = 0; kb < 512; kb += 32) {
        __syncthreads();                 // prev-iter frag reads complete
        *(u16x8*)&A_l[srow * 40 + sc8 * 8]        = pa;
        *(u16x8*)&B_l[srow * 40 + sc8 * 8]        = pb0;
        *(u16x8*)&B_l[(srow + 64) * 40 + sc8 * 8] = pb1;
        __syncthreads();

        if (kb + 32 < 512) PFETCH(kb + 32)   // issue-early: hides under MFMA

        short8 af[4], bf[2];
#pragma unroll
        for (int s = 0; s < 4; s++)
            af[s] = *(const short8*)&A_l[(s * 16 + am) * 40 + ak * 8];
#pragma unroll
        for (int u = 0; u < 2; u++)
            bf[u] = *(const short8*)&B_l[(wn + u * 16 + am) * 40 + ak * 8];
#pragma unroll
        for (int s = 0; s < 4; s++)
#pragma unroll
            for (int u = 0; u < 2; u++)
                acc[s][u] = __builtin_amdgcn_mfma_f32_16x16x32_bf16(af[s], bf[u], acc[s][u], 0, 0, 0);
    }
#undef PFETCH

#pragma unroll
    for (int s = 0; s < 4; s++) {
        const int o_base = ob + s * 16 + (lane >> 4) * 4;
#pragma unroll
        for (int r = 0; r < 4; r++) {
            const int o = o_base + r;
            const float inv = gamma[o] * rsqrtf(var[o] + BN_EPS);
            const float sh  = beta[o] - mean[o] * inv;
#pragma unroll
            for (int u = 0; u < 2; u++) {
                const int n = nb + wn + u * 16 + am;
                const size_t idx = ((size_t)b * 256 + o) * HW + n;
                out[idx] = x[idx] + acc[s][u][r] * inv + sh;
            }
        }
    }
}

extern "C" void kernel_launch(void* const* d_in, const int* in_sizes, int n_in,
                              void* d_out, int out_size, void* d_ws, size_t ws_size,
                              hipStream_t stream) {
    const float* x      = (const float*)d_in[0];
    const float* w_qkv  = (const float*)d_in[1];
    const float* w_dw   = (const float*)d_in[2];
    const float* w_pw   = (const float*)d_in[3];
    const float* w_proj = (const float*)d_in[4];
    const float* gamma  = (const float*)d_in[5];
    const float* beta   = (const float*)d_in[6];
    const float* mean   = (const float*)d_in[7];
    const float* var    = (const float*)d_in[8];
    float* out = (float*)d_out;

    unsigned short* qkv  = (unsigned short*)d_ws;      // 25165824 shorts
    unsigned short* agg  = qkv + (size_t)25165824;     // 25165824 shorts
    unsigned short* attf = agg + (size_t)25165824;     // 16777216 shorts
    unsigned short* wbf  = attf + (size_t)16777216;    // 131072 shorts
    float* kvb = (float*)(wbf + (size_t)131072);       // 36864 floats
    float* kvpart = (float*)attf;                      // 16*36864 f32, transient
    unsigned short* wqbf = attf + (size_t)4194304;     // 196608 shorts, transient
    unsigned short* xt   = agg;                        // 8388608 shorts, transient
                                                       // (agg written later by dw_agg)

    prep_wb <<<dim3(320),       256, 0, stream>>>(w_proj, w_qkv, wbf, wqbf);
    prep_xt <<<dim3(64, 4, 8),  256, 0, stream>>>(x, xt);
    qkv_gemm<<<dim3(32, 6, 8),  256, 0, stream>>>(xt, wqbf, qkv);
    dw_agg  <<<dim3(4, 96, 8),  256, 0, stream>>>(qkv, w_dw, w_pw, agg);
    kv_pass <<<dim3(8, 8, 16),  256, 0, stream>>>(qkv, agg, kvpart);
    kv_red  <<<dim3(144),       256, 0, stream>>>(kvpart, kvb);
    att_pass<<<dim3(2, 64, 8),  256, 0, stream>>>(qkv, agg, kvb, attf);
    proj_gemm<<<dim3(32, 4, 8), 256, 0, stream>>>(wbf, attf,
                                                  gamma, beta, mean, var, x, out);
}